// Round 2
// baseline (1326.837 us; speedup 1.0000x reference)
//
#include <hip/hip_runtime.h>
#include <hip/hip_bf16.h>

typedef __attribute__((ext_vector_type(8))) short short8;
typedef __attribute__((ext_vector_type(4))) float f32x4;
typedef unsigned short u16;

#define T_ 4096
#define D_ 1024

__device__ __forceinline__ u16 f2bf(float f) {
  union { float f; unsigned u; } v; v.f = f;
  unsigned r = v.u + 0x7FFFu + ((v.u >> 16) & 1u);
  return (u16)(r >> 16);
}
__device__ __forceinline__ float bf2f(u16 u) {
  union { unsigned u; float f; } v; v.u = ((unsigned)u) << 16; return v.f;
}

// ---------- pooling + fp32->bf16 convert ----------
__global__ __launch_bounds__(256) void pool_x(const float* __restrict__ x,
                                              u16* __restrict__ dst, int Tk, int stride) {
  const int r = blockIdx.x;
  const int b = r / Tk, t = r - b * Tk;
  const float* src = x + ((long)b * T_ + (long)t * stride) * D_;
  const float inv = 1.0f / (float)stride;
  for (int c = threadIdx.x; c < D_; c += 256) {
    float s = 0.f;
    for (int j = 0; j < stride; ++j) s += src[j * D_ + c];
    dst[(long)r * D_ + c] = f2bf(s * inv);
  }
}

// ---------- weight transposes (fp32 -> bf16, [K][N] -> [N][K]) ----------
__global__ __launch_bounds__(256) void wq_t(const float* __restrict__ Wq, u16* __restrict__ dst) {
  const int h = blockIdx.z;
  const int idx = blockIdx.x * 256 + threadIdx.x;   // 131072 per head
  const int c = idx >> 10, k = idx & 1023;
  dst[(long)h * 131072 + idx] = f2bf(Wq[(long)h * 131072 + k * 128 + c]);
}

__global__ __launch_bounds__(256) void wkv_t(const float* __restrict__ Wk, const float* __restrict__ Wv,
                                             u16* __restrict__ dst) {
  const int g = blockIdx.z;
  const int idx = blockIdx.x * 256 + threadIdx.x;   // 524288 per group
  const int n = idx >> 10, k = idx & 1023;
  const int kv = n >> 8, hh = (n >> 7) & 1, c = n & 127;
  const float* W = kv ? Wv : Wk;
  dst[(long)g * 524288 + idx] = f2bf(W[(long)(2 * g + hh) * 131072 + k * 128 + c]);
}

__global__ __launch_bounds__(256) void t_f32(const float* __restrict__ src, u16* __restrict__ dst,
                                             int R, int C) {
  const int idx = blockIdx.x * 256 + threadIdx.x;
  const int n = idx / R, k = idx - n * R;
  dst[idx] = f2bf(src[(long)k * C + n]);
}

// ---------- bf16 tiled transpose for K,V slices ----------
__global__ __launch_bounds__(256) void tpose_kv(const u16* __restrict__ kvg, u16* __restrict__ KT,
                                                u16* __restrict__ VT, int Tk) {
  __shared__ u16 tile[32][33];
  const int z = blockIdx.z;
  const int b = z & 1, hh = (z >> 1) & 1, kv = z >> 2;
  const u16* src = kvg + (long)b * Tk * 512 + kv * 256 + hh * 128;
  u16* dst = (kv ? VT : KT) + (long)(hh * 2 + b) * 128 * Tk;
  const int r0 = blockIdx.x * 32, c0 = blockIdx.y * 32;
  const int ci = threadIdx.x & 31, ri = threadIdx.x >> 5;
#pragma unroll
  for (int j = 0; j < 4; ++j)
    tile[ri + 8 * j][ci] = src[(long)(r0 + ri + 8 * j) * 512 + c0 + ci];
  __syncthreads();
#pragma unroll
  for (int j = 0; j < 4; ++j)
    dst[(long)(c0 + ri + 8 * j) * Tk + r0 + ci] = tile[ci][ri + 8 * j];
}

// ---------- irfft of per-head gains -> conv kernel c ----------
__global__ __launch_bounds__(256) void irfft_c(const float* __restrict__ bg, float* __restrict__ cbuf) {
  const int h = blockIdx.y;
  const int Tk = 4096 >> (h >> 1);
  if ((int)(blockIdx.x * 256) >= Tk) return;
  const int nb = (Tk >> 1) + 1;
  __shared__ float ct[4096];
  __shared__ float wm[2049];
  const int tid = threadIdx.x;
  const float w0 = 6.283185307179586f / (float)Tk;
  for (int j = tid; j < Tk; j += 256) ct[j] = cosf(w0 * (float)j);
  for (int m = tid; m < nb; m += 256) {
    int band = (m * 8) / nb; if (band > 7) band = 7;
    const float g = 1.f / (1.f + expf(-bg[h * 8 + band]));
    const float sc = (m == 0 || m == nb - 1) ? 1.f : 2.f;
    wm[m] = g * sc / (float)Tk;
  }
  __syncthreads();
  const int n = blockIdx.x * 256 + tid;
  float acc = 0.f;
  int idx = 0;
  for (int m = 0; m < nb; ++m) {
    acc += wm[m] * ct[idx];
    idx += n;
    if (idx >= Tk) idx -= Tk;
  }
  cbuf[h * 4096 + n] = acc;
}

// ---------- materialize circulant C[k][j] = c[(k-j) mod Tk] in bf16 ----------
__global__ __launch_bounds__(256) void cgen(const float* __restrict__ cbuf, u16* __restrict__ C,
                                            int hofs, int lg) {
  const long idx = (long)blockIdx.x * 256 + threadIdx.x;
  const int mask = (1 << lg) - 1;
  const int row = (int)(idx >> lg), col = (int)idx & mask;
  C[idx] = f2bf(cbuf[hofs + ((row - col) & mask)]);
}

// ---------- generic bf16 MFMA GEMM: C[m,n] = alpha * sum_k A[m,k]*Bt[n,k] ----------
__device__ __forceinline__ void gll16(const void* g, void* l) {
  __builtin_amdgcn_global_load_lds((const __attribute__((address_space(1))) void*)g,
                                   (__attribute__((address_space(3))) void*)l, 16, 0, 0);
}

template <bool OBF>
__global__ __launch_bounds__(256) void gemm_bt(const u16* __restrict__ A, const u16* __restrict__ Bt,
                                               void* __restrict__ Cv, int K, int lda, int ldb, int ldc,
                                               long abs_, long bbs, long cbs, float alpha) {
  __shared__ u16 lds[2][2][128][32];
  const int tid = threadIdx.x, lane = tid & 63, wid = tid >> 6;
  A += (long)blockIdx.z * abs_;
  Bt += (long)blockIdx.z * bbs;
  const int tm = blockIdx.x * 128, tn = blockIdx.y * 128;
  const int wr = wid >> 1, wc = wid & 1;
  const int srow = lane >> 2, scol = (lane & 3) * 8;
  const u16* ga0 = A + (long)(tm + 32 * wid + srow) * lda + scol;
  const u16* ga1 = ga0 + (long)16 * lda;
  const u16* gb0 = Bt + (long)(tn + 32 * wid + srow) * ldb + scol;
  const u16* gb1 = gb0 + (long)16 * ldb;
  f32x4 acc[4][4] = {};
  const int nk = K >> 5;
  gll16(ga0, &lds[0][0][32 * wid][0]);
  gll16(ga1, &lds[0][0][32 * wid + 16][0]);
  gll16(gb0, &lds[0][1][32 * wid][0]);
  gll16(gb1, &lds[0][1][32 * wid + 16][0]);
  int buf = 0;
  const int fr = lane & 15, fo = (lane >> 4) * 8;
  for (int kt = 0; kt < nk; ++kt) {
    __syncthreads();
    if (kt + 1 < nk) {
      const long ko = (long)(kt + 1) * 32;
      gll16(ga0 + ko, &lds[buf ^ 1][0][32 * wid][0]);
      gll16(ga1 + ko, &lds[buf ^ 1][0][32 * wid + 16][0]);
      gll16(gb0 + ko, &lds[buf ^ 1][1][32 * wid][0]);
      gll16(gb1 + ko, &lds[buf ^ 1][1][32 * wid + 16][0]);
    }
    short8 af[4], bfr[4];
#pragma unroll
    for (int i = 0; i < 4; ++i) {
      af[i]  = *(const short8*)&lds[buf][0][wr * 64 + i * 16 + fr][fo];
      bfr[i] = *(const short8*)&lds[buf][1][wc * 64 + i * 16 + fr][fo];
    }
#pragma unroll
    for (int i = 0; i < 4; ++i)
#pragma unroll
      for (int j = 0; j < 4; ++j)
        acc[i][j] = __builtin_amdgcn_mfma_f32_16x16x32_bf16(af[i], bfr[j], acc[i][j], 0, 0, 0);
    buf ^= 1;
  }
  const int er = (lane >> 4) * 4, ec = lane & 15;
  if constexpr (OBF) {
    u16* C = (u16*)Cv + (long)blockIdx.z * cbs;
#pragma unroll
    for (int i = 0; i < 4; ++i)
#pragma unroll
      for (int j = 0; j < 4; ++j)
#pragma unroll
        for (int r = 0; r < 4; ++r)
          C[(long)(tm + wr * 64 + i * 16 + er + r) * ldc + (tn + wc * 64 + j * 16 + ec)] =
              f2bf(acc[i][j][r] * alpha);
  } else {
    float* C = (float*)Cv + (long)blockIdx.z * cbs;
#pragma unroll
    for (int i = 0; i < 4; ++i)
#pragma unroll
      for (int j = 0; j < 4; ++j)
#pragma unroll
        for (int r = 0; r < 4; ++r)
          C[(long)(tm + wr * 64 + i * 16 + er + r) * ldc + (tn + wc * 64 + j * 16 + ec)] =
              acc[i][j][r] * alpha;
  }
}

// ---------- in-place row softmax on bf16 S ----------
template <int NU>
__global__ __launch_bounds__(256) void softmax_bf(u16* __restrict__ S, int Tk) {
  const long row = blockIdx.x;
  u16* s = S + row * (long)Tk;
  const int tid = threadIdx.x;
  const int nu = Tk >> 3;   // short8 units in the row
  float f[NU][8];
  float m = -1e30f;
#pragma unroll
  for (int i = 0; i < NU; ++i) {
    const int u = tid + i * 256;
    if (u < nu) {
      short8 v = ((const short8*)s)[u];
#pragma unroll
      for (int j = 0; j < 8; ++j) { f[i][j] = bf2f((u16)v[j]); m = fmaxf(m, f[i][j]); }
    }
  }
#pragma unroll
  for (int o = 1; o < 64; o <<= 1) m = fmaxf(m, __shfl_xor(m, o));
  __shared__ float r1[4], r2[4];
  if ((tid & 63) == 0) r1[tid >> 6] = m;
  __syncthreads();
  m = fmaxf(fmaxf(r1[0], r1[1]), fmaxf(r1[2], r1[3]));
  float sum = 0.f;
#pragma unroll
  for (int i = 0; i < NU; ++i) {
    const int u = tid + i * 256;
    if (u < nu)
#pragma unroll
      for (int j = 0; j < 8; ++j) { f[i][j] = __expf(f[i][j] - m); sum += f[i][j]; }
  }
#pragma unroll
  for (int o = 1; o < 64; o <<= 1) sum += __shfl_xor(sum, o);
  if ((tid & 63) == 0) r2[tid >> 6] = sum;
  __syncthreads();
  const float inv = 1.f / (r2[0] + r2[1] + r2[2] + r2[3]);
#pragma unroll
  for (int i = 0; i < NU; ++i) {
    const int u = tid + i * 256;
    if (u < nu) {
      short8 v;
#pragma unroll
      for (int j = 0; j < 8; ++j) v[j] = (short)f2bf(f[i][j] * inv);
      ((short8*)s)[u] = v;
    }
  }
}

// ---------- fused router MLP tail + contra-flow + head mixing ----------
__global__ __launch_bounds__(256) void router_mix(const float* __restrict__ hid,
    const float* __restrict__ rb1, const float* __restrict__ rW2, const float* __restrict__ rb2,
    const float* __restrict__ al, const float* __restrict__ O, u16* __restrict__ mixed) {
  const int tok = blockIdx.x;
  const int b = tok >> 12, t = tok & 4095;
  const int tid = threadIdx.x;
  __shared__ float lred[4][8];
  __shared__ float wgt[8];
  __shared__ float ta[8];
  const float hv = fmaxf(hid[(long)tok * 256 + tid] + rb1[tid], 0.f);
  const float4* w4 = (const float4*)(rW2 + tid * 8);
  const float4 wa = w4[0], wb = w4[1];
  float part[8] = {hv * wa.x, hv * wa.y, hv * wa.z, hv * wa.w,
                   hv * wb.x, hv * wb.y, hv * wb.z, hv * wb.w};
#pragma unroll
  for (int h = 0; h < 8; ++h) {
    float v = part[h];
#pragma unroll
    for (int o = 1; o < 64; o <<= 1) v += __shfl_xor(v, o);
    if ((tid & 63) == 0) lred[tid >> 6][h] = v;
  }
  __syncthreads();
  if (tid < 8) ta[tid] = tanhf(al[tid]);
  if (tid == 0) {
    float lg[8], m = -1e30f;
#pragma unroll
    for (int h = 0; h < 8; ++h) {
      lg[h] = lred[0][h] + lred[1][h] + lred[2][h] + lred[3][h] + rb2[h];
      m = fmaxf(m, lg[h]);
    }
    float s = 0.f;
#pragma unroll
    for (int h = 0; h < 8; ++h) { lg[h] = __expf(lg[h] - m); s += lg[h]; }
    const float inv = 1.f / s;
#pragma unroll
    for (int h = 0; h < 8; ++h) wgt[h] = lg[h] * inv;
  }
  __syncthreads();
  if (tid < 128) {
    const long base = (long)tok * 1024 + tid;
    const long rbase = ((long)b * 4096 + (4095 - t)) * 1024 + tid;
    float acc = 0.f;
#pragma unroll
    for (int h = 0; h < 8; ++h)
      acc += wgt[h] * (O[base + h * 128] + ta[h] * O[rbase + h * 128]);
    mixed[(long)tok * 128 + tid] = f2bf(acc);
  }
}

extern "C" void kernel_launch(void* const* d_in, const int* in_sizes, int n_in,
                              void* d_out, int out_size, void* d_ws, size_t ws_size,
                              hipStream_t stream) {
  const float* x    = (const float*)d_in[0];
  const float* Wq   = (const float*)d_in[1];
  const float* Wk   = (const float*)d_in[2];
  const float* Wv   = (const float*)d_in[3];
  const float* bg   = (const float*)d_in[4];
  const float* al   = (const float*)d_in[5];
  const float* rW1  = (const float*)d_in[6];
  const float* rb1  = (const float*)d_in[7];
  const float* rW2  = (const float*)d_in[8];
  const float* rb2  = (const float*)d_in[9];
  const float* Wout = (const float*)d_in[10];
  float* out = (float*)d_out;

  // ---- 127 MB arena with lifetime-based overlays ----
  const size_t MB = 1u << 20;
  char* w = (char*)d_ws;
  // Region A [0,32MB): phase1 = x pools; phase3 = Cc; phase4+ = O (fp32)
  u16*   xbf   = (u16*)(w + 0);            // 16 MB [P0-P1]
  u16*   xp2   = (u16*)(w + 16 * MB);      //  8 MB [P0-P1]
  u16*   xp4   = (u16*)(w + 24 * MB);      //  4 MB [P0-P1]
  u16*   xp8   = (u16*)(w + 28 * MB);      //  2 MB [P0-P1]
  u16*   Cc    = (u16*)(w + 0);            // 32 MB [P3]
  float* O     = (float*)(w + 0);          // 32 MB [P4-P5]
  u16*   Qb    = (u16*)(w + 32 * MB);      // 16 MB [P1-P4]
  u16*   KV    = (u16*)(w + 48 * MB);      // 15 MB [P1-P2]
  u16*   Kp    = (u16*)(w + 48 * MB);      // 7.5MB [P3-P4] (overlays dead KV)
  u16*   KT    = (u16*)(w + 63 * MB);      // 7.5MB [P2-P3]
  u16*   VT    = (u16*)(w + 70 * MB + 512 * 1024); // 7.5MB [P2-P4]
  u16*   S     = (u16*)(w + 78 * MB);      // 32 MB bf16 [P4], softmax in place
  float* hid   = (float*)(w + 110 * MB);   //  8 MB [P1-P5]
  u16*   wqT   = (u16*)(w + 118 * MB);     //  2 MB
  u16*   kvT   = (u16*)(w + 120 * MB);     //  4 MB
  u16*   rw1T  = (u16*)(w + 124 * MB);     // 512 KB
  u16*   woutT = (u16*)(w + 124 * MB + 512 * 1024);  // 256 KB
  float* cbuf  = (float*)(w + 124 * MB + 768 * 1024); // 128 KB
  u16*   mixed = (u16*)(w + 125 * MB);     //  2 MB
  // total = 127 MB

  auto gemm = [&](const void* A, const void* Bt, void* C, int M, int N, int K,
                  int lda, int ldb, int ldc, long abs_, long bbs, long cbs,
                  int nz, float alpha, bool obf) {
    dim3 g(M / 128, N / 128, nz), blk(256);
    if (obf)
      gemm_bt<true><<<g, blk, 0, stream>>>((const u16*)A, (const u16*)Bt, C, K, lda, ldb, ldc, abs_, bbs, cbs, alpha);
    else
      gemm_bt<false><<<g, blk, 0, stream>>>((const u16*)A, (const u16*)Bt, C, K, lda, ldb, ldc, abs_, bbs, cbs, alpha);
  };

  // P0: pooling + weight transposes
  pool_x<<<dim3(8192), dim3(256), 0, stream>>>(x, xbf, 4096, 1);
  pool_x<<<dim3(4096), dim3(256), 0, stream>>>(x, xp2, 2048, 2);
  pool_x<<<dim3(2048), dim3(256), 0, stream>>>(x, xp4, 1024, 4);
  pool_x<<<dim3(1024), dim3(256), 0, stream>>>(x, xp8, 512, 8);
  wq_t<<<dim3(512, 1, 8), dim3(256), 0, stream>>>(Wq, wqT);
  wkv_t<<<dim3(2048, 1, 4), dim3(256), 0, stream>>>(Wk, Wv, kvT);
  t_f32<<<dim3(1024), dim3(256), 0, stream>>>(rW1, rw1T, 1024, 256);
  t_f32<<<dim3(512), dim3(256), 0, stream>>>(Wout, woutT, 128, 1024);

  // P1: projections + router hidden (everything that reads x pools)
  gemm(xbf, wqT, Qb, 8192, 1024, 1024, 1024, 1024, 1024, 0, 0, 0, 1, 1.f, true);
  const u16* xps[4] = {xbf, xp2, xp4, xp8};
  const long kvrow[4] = {0, 8192, 12288, 14336};
  const long ktoff[4] = {0, 2097152, 3145728, 3670016};
  const long kpoff[8] = {0, 1048576, 2097152, 2621440, 3145728, 3407872, 3670016, 3801088};
  for (int g = 0; g < 4; ++g) {
    const int Tk = 4096 >> g;
    gemm(xps[g], kvT + (long)g * 524288, KV + kvrow[g] * 512, 2 * Tk, 512, 1024,
         1024, 1024, 512, 0, 0, 0, 1, 1.f, true);
  }
  gemm(xbf, rw1T, hid, 8192, 256, 1024, 1024, 1024, 256, 0, 0, 0, 1, 1.f, false);

  // P2: K/V transposes + spectral kernel
  for (int g = 0; g < 4; ++g) {
    const int Tk = 4096 >> g;
    tpose_kv<<<dim3(Tk / 32, 4, 8), dim3(256), 0, stream>>>(KV + kvrow[g] * 512, KT + ktoff[g], VT + ktoff[g], Tk);
  }
  irfft_c<<<dim3(16, 8), dim3(256), 0, stream>>>(bg, cbuf);

  // P3: pre-convolve K with circulant spectral kernel (Kp = C * K), per head
  for (int h = 0; h < 8; ++h) {
    const int g = h >> 1, Tk = 4096 >> g, lg = 12 - g;
    cgen<<<dim3((Tk * Tk) / 256), dim3(256), 0, stream>>>(cbuf, Cc, h * 4096, lg);
    const u16* kth = KT + ktoff[g] + (long)(h & 1) * 2 * 128 * Tk;
    gemm(Cc, kth, Kp + kpoff[h], Tk, 128, Tk, Tk, Tk, 128,
         0, (long)128 * Tk, (long)Tk * 128, 2, 1.f, true);
  }

  // P4: attention per (head, batch): S = Q·Kp^T (bf16) -> softmax in place -> O = P·V
  const float iss = 0.08838834764831845f;  // 1/sqrt(128)
  for (int h = 0; h < 8; ++h) {
    const int g = h >> 1, Tk = 4096 >> g;
    for (int b = 0; b < 2; ++b) {
      gemm(Qb + (long)b * 4096 * 1024 + h * 128, Kp + kpoff[h] + (long)b * Tk * 128, S,
           4096, Tk, 128, 1024, 128, Tk, 0, 0, 0, 1, iss, true);
      if (Tk == 4096) softmax_bf<2><<<dim3(4096), dim3(256), 0, stream>>>(S, Tk);
      else            softmax_bf<1><<<dim3(4096), dim3(256), 0, stream>>>(S, Tk);
      const u16* vth = VT + ktoff[g] + ((long)(h & 1) * 2 + b) * 128 * Tk;
      gemm(S, vth, O + ((long)b * 4096 * 8 + h) * 128, 4096, 128, Tk,
           Tk, Tk, 1024, 0, 0, 0, 1, 1.f, false);
    }
  }

  // P5: router softmax + contra-flow mix, then output projection
  router_mix<<<dim3(8192), dim3(256), 0, stream>>>(hid, rb1, rW2, rb2, al, O, mixed);
  gemm(mixed, woutT, out, 8192, 1024, 128, 128, 128, 1024, 0, 0, 0, 1, 1.f, false);
}

// Round 3
// 467.276 us; speedup vs baseline: 2.8395x; 2.8395x over previous
//
#include <hip/hip_runtime.h>
#include <hip/hip_bf16.h>

typedef __attribute__((ext_vector_type(8))) short short8;
typedef __attribute__((ext_vector_type(4))) float f32x4;
typedef unsigned short u16;

#define T_ 4096
#define D_ 1024
#define ISS 0.08838834764831845f

__device__ __forceinline__ u16 f2bf(float f) {
  union { float f; unsigned u; } v; v.f = f;
  unsigned r = v.u + 0x7FFFu + ((v.u >> 16) & 1u);
  return (u16)(r >> 16);
}

// ---------- fused 4-way pooling, fp32 -> bf16 ----------
__global__ __launch_bounds__(256) void pool_all(const float* __restrict__ x,
    u16* __restrict__ p1, u16* __restrict__ p2, u16* __restrict__ p4, u16* __restrict__ p8) {
  const int blk = blockIdx.x;                 // 1024 blocks, 8 time-rows each
  const int b = blk >> 9, t0 = (blk & 511) << 3;
  const float* src = x + ((long)b * T_ + t0) * D_;
#pragma unroll
  for (int j = 0; j < 4; ++j) {
    const int c = threadIdx.x + j * 256;
    float v[8];
#pragma unroll
    for (int r = 0; r < 8; ++r) v[r] = src[r * D_ + c];
#pragma unroll
    for (int r = 0; r < 8; ++r) p1[((long)b * 4096 + t0 + r) * D_ + c] = f2bf(v[r]);
#pragma unroll
    for (int r = 0; r < 4; ++r)
      p2[((long)b * 2048 + (t0 >> 1) + r) * D_ + c] = f2bf((v[2*r] + v[2*r+1]) * 0.5f);
#pragma unroll
    for (int r = 0; r < 2; ++r)
      p4[((long)b * 1024 + (t0 >> 2) + r) * D_ + c] =
          f2bf((v[4*r] + v[4*r+1] + v[4*r+2] + v[4*r+3]) * 0.25f);
    p8[((long)b * 512 + (t0 >> 3)) * D_ + c] =
        f2bf((v[0]+v[1]+v[2]+v[3]+v[4]+v[5]+v[6]+v[7]) * 0.125f);
  }
}

// ---------- weight transposes (fp32 -> bf16, [K][N] -> [N][K]) ----------
__global__ __launch_bounds__(256) void wq_t(const float* __restrict__ Wq, u16* __restrict__ dst) {
  const int h = blockIdx.z;
  const int idx = blockIdx.x * 256 + threadIdx.x;
  const int c = idx >> 10, k = idx & 1023;
  dst[(long)h * 131072 + idx] = f2bf(Wq[(long)h * 131072 + k * 128 + c]);
}

__global__ __launch_bounds__(256) void wkv_t(const float* __restrict__ Wk, const float* __restrict__ Wv,
                                             u16* __restrict__ dst) {
  const int g = blockIdx.z;
  const int idx = blockIdx.x * 256 + threadIdx.x;
  const int n = idx >> 10, k = idx & 1023;
  const int kv = n >> 8, hh = (n >> 7) & 1, c = n & 127;
  const float* W = kv ? Wv : Wk;
  dst[(long)g * 524288 + idx] = f2bf(W[(long)(2 * g + hh) * 131072 + k * 128 + c]);
}

__global__ __launch_bounds__(256) void t_f32(const float* __restrict__ src, u16* __restrict__ dst,
                                             int R, int C) {
  const int idx = blockIdx.x * 256 + threadIdx.x;
  const int n = idx / R, k = idx - n * R;
  dst[idx] = f2bf(src[(long)k * C + n]);
}

// ---------- bf16 tiled transpose for K,V slices ----------
__global__ __launch_bounds__(256) void tpose_kv(const u16* __restrict__ kvg, u16* __restrict__ KT,
                                                u16* __restrict__ VT, int Tk) {
  __shared__ u16 tile[32][33];
  const int z = blockIdx.z;
  const int b = z & 1, hh = (z >> 1) & 1, kv = z >> 2;
  const u16* src = kvg + (long)b * Tk * 512 + kv * 256 + hh * 128;
  u16* dst = (kv ? VT : KT) + (long)(hh * 2 + b) * 128 * Tk;
  const int r0 = blockIdx.x * 32, c0 = blockIdx.y * 32;
  const int ci = threadIdx.x & 31, ri = threadIdx.x >> 5;
#pragma unroll
  for (int j = 0; j < 4; ++j)
    tile[ri + 8 * j][ci] = src[(long)(r0 + ri + 8 * j) * 512 + c0 + ci];
  __syncthreads();
#pragma unroll
  for (int j = 0; j < 4; ++j)
    dst[(long)(c0 + ri + 8 * j) * Tk + r0 + ci] = tile[ci][ri + 8 * j];
}

// ---------- irfft of per-head gains -> conv kernel c ----------
__global__ __launch_bounds__(256) void irfft_c(const float* __restrict__ bg, float* __restrict__ cbuf) {
  const int h = blockIdx.y;
  const int Tk = 4096 >> (h >> 1);
  if ((int)(blockIdx.x * 256) >= Tk) return;
  const int nb = (Tk >> 1) + 1;
  __shared__ float ct[4096];
  __shared__ float wm[2049];
  const int tid = threadIdx.x;
  const float w0 = 6.283185307179586f / (float)Tk;
  for (int j = tid; j < Tk; j += 256) ct[j] = cosf(w0 * (float)j);
  for (int m = tid; m < nb; m += 256) {
    int band = (m * 8) / nb; if (band > 7) band = 7;
    const float g = 1.f / (1.f + expf(-bg[h * 8 + band]));
    const float sc = (m == 0 || m == nb - 1) ? 1.f : 2.f;
    wm[m] = g * sc / (float)Tk;
  }
  __syncthreads();
  const int n = blockIdx.x * 256 + tid;
  float acc = 0.f;
  int idx = 0;
  for (int m = 0; m < nb; ++m) {
    acc += wm[m] * ct[idx];
    idx += n;
    if (idx >= Tk) idx -= Tk;
  }
  cbuf[h * 4096 + n] = acc;
}

// ---------- async global->LDS ----------
__device__ __forceinline__ void gll16(const void* g, void* l) {
  __builtin_amdgcn_global_load_lds((const __attribute__((address_space(1))) void*)g,
                                   (__attribute__((address_space(3))) void*)l, 16, 0, 0);
}

// ---------- generic bf16 MFMA GEMM: C[m,n] = alpha * sum_k A[m,k]*Bt[n,k] ----------
template <bool OBF>
__global__ __launch_bounds__(256) void gemm_bt(const u16* __restrict__ A, const u16* __restrict__ Bt,
                                               void* __restrict__ Cv, int K, int lda, int ldb, int ldc,
                                               long abs_, long bbs, long cbs, float alpha) {
  __shared__ u16 lds[2][2][128][32];
  const int tid = threadIdx.x, lane = tid & 63, wid = tid >> 6;
  A += (long)blockIdx.z * abs_;
  Bt += (long)blockIdx.z * bbs;
  const int tm = blockIdx.x * 128, tn = blockIdx.y * 128;
  const int wr = wid >> 1, wc = wid & 1;
  const int srow = lane >> 2, scol = (lane & 3) * 8;
  const u16* ga0 = A + (long)(tm + 32 * wid + srow) * lda + scol;
  const u16* ga1 = ga0 + (long)16 * lda;
  const u16* gb0 = Bt + (long)(tn + 32 * wid + srow) * ldb + scol;
  const u16* gb1 = gb0 + (long)16 * ldb;
  f32x4 acc[4][4] = {};
  const int nk = K >> 5;
  gll16(ga0, &lds[0][0][32 * wid][0]);
  gll16(ga1, &lds[0][0][32 * wid + 16][0]);
  gll16(gb0, &lds[0][1][32 * wid][0]);
  gll16(gb1, &lds[0][1][32 * wid + 16][0]);
  int buf = 0;
  const int fr = lane & 15, fo = (lane >> 4) * 8;
  for (int kt = 0; kt < nk; ++kt) {
    __syncthreads();
    if (kt + 1 < nk) {
      const long ko = (long)(kt + 1) * 32;
      gll16(ga0 + ko, &lds[buf ^ 1][0][32 * wid][0]);
      gll16(ga1 + ko, &lds[buf ^ 1][0][32 * wid + 16][0]);
      gll16(gb0 + ko, &lds[buf ^ 1][1][32 * wid][0]);
      gll16(gb1 + ko, &lds[buf ^ 1][1][32 * wid + 16][0]);
    }
    short8 af[4], bfr[4];
#pragma unroll
    for (int i = 0; i < 4; ++i) {
      af[i]  = *(const short8*)&lds[buf][0][wr * 64 + i * 16 + fr][fo];
      bfr[i] = *(const short8*)&lds[buf][1][wc * 64 + i * 16 + fr][fo];
    }
#pragma unroll
    for (int i = 0; i < 4; ++i)
#pragma unroll
      for (int j = 0; j < 4; ++j)
        acc[i][j] = __builtin_amdgcn_mfma_f32_16x16x32_bf16(af[i], bfr[j], acc[i][j], 0, 0, 0);
    buf ^= 1;
  }
  const int er = (lane >> 4) * 4, ec = lane & 15;
  if constexpr (OBF) {
    u16* C = (u16*)Cv + (long)blockIdx.z * cbs;
#pragma unroll
    for (int i = 0; i < 4; ++i)
#pragma unroll
      for (int j = 0; j < 4; ++j)
#pragma unroll
        for (int r = 0; r < 4; ++r)
          C[(long)(tm + wr * 64 + i * 16 + er + r) * ldc + (tn + wc * 64 + j * 16 + ec)] =
              f2bf(acc[i][j][r] * alpha);
  } else {
    float* C = (float*)Cv + (long)blockIdx.z * cbs;
#pragma unroll
    for (int i = 0; i < 4; ++i)
#pragma unroll
      for (int j = 0; j < 4; ++j)
#pragma unroll
        for (int r = 0; r < 4; ++r)
          C[(long)(tm + wr * 64 + i * 16 + er + r) * ldc + (tn + wc * 64 + j * 16 + ec)] =
              acc[i][j][r] * alpha;
  }
}

// ---------- circulant conv GEMM: Kp[m,n] = ISS * sum_k c[(k-m)&mask] * K[k,n] ----------
// one launch covers all (h,b); A-fragments read directly from c in LDS (c is even-symmetric)
__global__ __launch_bounds__(256) void conv_k(const float* __restrict__ cbuf,
    const u16* __restrict__ KT, u16* __restrict__ Kp) {
  const int z = blockIdx.z, h = z >> 1, b = z & 1, g = h >> 1;
  const int Tk = 4096 >> g, mask = Tk - 1;
  const int tm = blockIdx.x << 7;
  if (tm >= Tk) return;
  __shared__ u16 clds[4104];
  __shared__ u16 blds[2][128][32];
  const int tid = threadIdx.x, lane = tid & 63, wid = tid >> 6;
  const int wr = wid >> 1, wc = wid & 1;
  const int srow = lane >> 2, scol = (lane & 3) * 8;
  const int fr = lane & 15, fo = (lane >> 4) * 8;
  for (int j = tid; j < Tk + 8; j += 256) clds[j] = f2bf(cbuf[h * 4096 + (j & mask)]);
  const long ktofs = 4194304 - (4194304 >> g);
  const u16* Bt = KT + ktofs + (long)((h & 1) * 2 + b) * 128 * Tk;
  u16* out = Kp + ktofs + ((long)(h & 1) << 8) * Tk + ((long)b << 7) * Tk;
  const u16* gb0 = Bt + (long)(32 * wid + srow) * Tk + scol;
  const u16* gb1 = gb0 + (long)16 * Tk;
  f32x4 acc[4][4] = {};
  int base[4];
#pragma unroll
  for (int i = 0; i < 4; ++i) base[i] = (fo - (tm + wr * 64 + i * 16 + fr)) & mask;
  const int nk = Tk >> 5;
  gll16(gb0, &blds[0][32 * wid][0]);
  gll16(gb1, &blds[0][32 * wid + 16][0]);
  int buf = 0;
  for (int kt = 0; kt < nk; ++kt) {
    __syncthreads();
    if (kt + 1 < nk) {
      const long ko = (long)(kt + 1) * 32;
      gll16(gb0 + ko, &blds[buf ^ 1][32 * wid][0]);
      gll16(gb1 + ko, &blds[buf ^ 1][32 * wid + 16][0]);
    }
    short8 af[4], bfr[4];
#pragma unroll
    for (int i = 0; i < 4; ++i) {
#pragma unroll
      for (int jj = 0; jj < 8; ++jj) af[i][jj] = (short)clds[base[i] + jj];
      base[i] = (base[i] + 32) & mask;
      bfr[i] = *(const short8*)&blds[buf][wc * 64 + i * 16 + fr][fo];
    }
#pragma unroll
    for (int i = 0; i < 4; ++i)
#pragma unroll
      for (int j = 0; j < 4; ++j)
        acc[i][j] = __builtin_amdgcn_mfma_f32_16x16x32_bf16(af[i], bfr[j], acc[i][j], 0, 0, 0);
    buf ^= 1;
  }
  const int er = (lane >> 4) * 4, ec = lane & 15;
#pragma unroll
  for (int i = 0; i < 4; ++i)
#pragma unroll
    for (int j = 0; j < 4; ++j)
#pragma unroll
      for (int r = 0; r < 4; ++r)
        out[(long)(tm + wr * 64 + i * 16 + er + r) * 128 + (wc * 64 + j * 16 + ec)] =
            f2bf(acc[i][j][r] * ISS);
}

// ---------- flash attention: S=Q·Kp^T (pre-scaled), online softmax, O=P·V ----------
__global__ __launch_bounds__(512) void flash(const u16* __restrict__ Qb,
    const u16* __restrict__ Kp, const u16* __restrict__ VT, float* __restrict__ O) {
  const int z = blockIdx.z, h = z >> 1, b = z & 1, g = h >> 1;
  const int Tk = 4096 >> g;
  const int qtm = blockIdx.x << 7;
  __shared__ u16 Klds[4][128][32];
  __shared__ u16 Vlds[4][128][32];
  __shared__ u16 Plds[128][136];
  const int tid = threadIdx.x, lane = tid & 63, wid = tid >> 6;
  const int fr = lane & 15, fo = (lane >> 4) * 8;
  const int srow = lane >> 2, scol = (lane & 3) * 8;
  const int rbase = (lane >> 4) * 4;
  // Q fragments in registers (rows qtm + wid*16 + fr)
  const u16* qptr = Qb + ((long)(b * 4096 + qtm + wid * 16 + fr) * 1024 + h * 128);
  short8 aq[4];
#pragma unroll
  for (int kk = 0; kk < 4; ++kk) aq[kk] = *(const short8*)(qptr + kk * 32 + fo);
  const long ktofs = 4194304 - (4194304 >> g);
  const u16* kbase = Kp + ktofs + ((long)(h & 1) << 8) * Tk + ((long)b << 7) * Tk;
  const u16* vbase = VT + ktofs + (long)((h & 1) * 2 + b) * 128 * Tk;
  f32x4 acc[8] = {};
  float mr[4], lr[4];
#pragma unroll
  for (int r = 0; r < 4; ++r) { mr[r] = -3e38f; lr[r] = 0.f; }
  const int nt = Tk >> 7;
  const u16* vsl = vbase + (long)(wid * 16 + srow) * Tk + scol;
  for (int kt = 0; kt < nt; ++kt) {
    // stage K tile (keys kt*128.., dims 128) in m97 chunk layout
    const u16* ksl = kbase + (long)(kt * 128 + wid * 16 + srow) * 128 + scol;
#pragma unroll
    for (int kk = 0; kk < 4; ++kk) gll16(ksl + kk * 32, &Klds[kk][wid * 16][0]);
    __syncthreads();
    // issue V stage now: latency hides under QK^T + softmax
#pragma unroll
    for (int kk = 0; kk < 4; ++kk) gll16(vsl + kt * 128 + kk * 32, &Vlds[kk][wid * 16][0]);
    // QK^T
    f32x4 sa[8] = {};
#pragma unroll
    for (int kk = 0; kk < 4; ++kk)
#pragma unroll
      for (int j = 0; j < 8; ++j) {
        short8 bk = *(const short8*)&Klds[kk][j * 16 + fr][fo];
        sa[j] = __builtin_amdgcn_mfma_f32_16x16x32_bf16(aq[kk], bk, sa[j], 0, 0, 0);
      }
    // online softmax (S already scaled by 1/sqrt(d) via Kp)
    float tmax[4];
#pragma unroll
    for (int r = 0; r < 4; ++r) tmax[r] = sa[0][r];
#pragma unroll
    for (int j = 1; j < 8; ++j)
#pragma unroll
      for (int r = 0; r < 4; ++r) tmax[r] = fmaxf(tmax[r], sa[j][r]);
#pragma unroll
    for (int r = 0; r < 4; ++r) {
      tmax[r] = fmaxf(tmax[r], __shfl_xor(tmax[r], 1));
      tmax[r] = fmaxf(tmax[r], __shfl_xor(tmax[r], 2));
      tmax[r] = fmaxf(tmax[r], __shfl_xor(tmax[r], 4));
      tmax[r] = fmaxf(tmax[r], __shfl_xor(tmax[r], 8));
    }
    float mn[4], al[4], ps[4];
#pragma unroll
    for (int r = 0; r < 4; ++r) {
      mn[r] = fmaxf(mr[r], tmax[r]);
      al[r] = __expf(mr[r] - mn[r]);
      ps[r] = 0.f;
    }
#pragma unroll
    for (int j = 0; j < 8; ++j)
#pragma unroll
      for (int r = 0; r < 4; ++r) {
        float p = __expf(sa[j][r] - mn[r]);
        sa[j][r] = p;
        ps[r] += p;
      }
#pragma unroll
    for (int r = 0; r < 4; ++r) {
      ps[r] += __shfl_xor(ps[r], 1);
      ps[r] += __shfl_xor(ps[r], 2);
      ps[r] += __shfl_xor(ps[r], 4);
      ps[r] += __shfl_xor(ps[r], 8);
      lr[r] = lr[r] * al[r] + ps[r];
      mr[r] = mn[r];
    }
#pragma unroll
    for (int jd = 0; jd < 8; ++jd)
#pragma unroll
      for (int r = 0; r < 4; ++r) acc[jd][r] *= al[r];
    // write P tile to LDS
#pragma unroll
    for (int j = 0; j < 8; ++j)
#pragma unroll
      for (int r = 0; r < 4; ++r)
        Plds[wid * 16 + rbase + r][j * 16 + (lane & 15)] = f2bf(sa[j][r]);
    __syncthreads();
    // PV
#pragma unroll
    for (int kk = 0; kk < 4; ++kk) {
      short8 ap = *(const short8*)&Plds[wid * 16 + fr][kk * 32 + fo];
#pragma unroll
      for (int jd = 0; jd < 8; ++jd) {
        short8 bv = *(const short8*)&Vlds[kk][jd * 16 + fr][fo];
        acc[jd] = __builtin_amdgcn_mfma_f32_16x16x32_bf16(ap, bv, acc[jd], 0, 0, 0);
      }
    }
    __syncthreads();
  }
  float inv[4];
#pragma unroll
  for (int r = 0; r < 4; ++r) inv[r] = 1.f / lr[r];
#pragma unroll
  for (int jd = 0; jd < 8; ++jd)
#pragma unroll
    for (int r = 0; r < 4; ++r) {
      const int row = qtm + wid * 16 + rbase + r;
      O[((long)(b * 4096 + row) * 8 + h) * 128 + jd * 16 + (lane & 15)] = acc[jd][r] * inv[r];
    }
}

// ---------- fused router MLP tail + contra-flow + head mixing ----------
__global__ __launch_bounds__(256) void router_mix(const float* __restrict__ hid,
    const float* __restrict__ rb1, const float* __restrict__ rW2, const float* __restrict__ rb2,
    const float* __restrict__ al, const float* __restrict__ O, u16* __restrict__ mixed) {
  const int tok = blockIdx.x;
  const int b = tok >> 12, t = tok & 4095;
  const int tid = threadIdx.x;
  __shared__ float lred[4][8];
  __shared__ float wgt[8];
  __shared__ float ta[8];
  const float hv = fmaxf(hid[(long)tok * 256 + tid] + rb1[tid], 0.f);
  const float4* w4 = (const float4*)(rW2 + tid * 8);
  const float4 wa = w4[0], wb = w4[1];
  float part[8] = {hv * wa.x, hv * wa.y, hv * wa.z, hv * wa.w,
                   hv * wb.x, hv * wb.y, hv * wb.z, hv * wb.w};
#pragma unroll
  for (int h = 0; h < 8; ++h) {
    float v = part[h];
#pragma unroll
    for (int o = 1; o < 64; o <<= 1) v += __shfl_xor(v, o);
    if ((tid & 63) == 0) lred[tid >> 6][h] = v;
  }
  __syncthreads();
  if (tid < 8) ta[tid] = tanhf(al[tid]);
  if (tid == 0) {
    float lg[8], m = -1e30f;
#pragma unroll
    for (int h = 0; h < 8; ++h) {
      lg[h] = lred[0][h] + lred[1][h] + lred[2][h] + lred[3][h] + rb2[h];
      m = fmaxf(m, lg[h]);
    }
    float s = 0.f;
#pragma unroll
    for (int h = 0; h < 8; ++h) { lg[h] = __expf(lg[h] - m); s += lg[h]; }
    const float inv = 1.f / s;
#pragma unroll
    for (int h = 0; h < 8; ++h) wgt[h] = lg[h] * inv;
  }
  __syncthreads();
  if (tid < 128) {
    const long base = (long)tok * 1024 + tid;
    const long rbase = ((long)b * 4096 + (4095 - t)) * 1024 + tid;
    float acc = 0.f;
#pragma unroll
    for (int h = 0; h < 8; ++h)
      acc += wgt[h] * (O[base + h * 128] + ta[h] * O[rbase + h * 128]);
    mixed[(long)tok * 128 + tid] = f2bf(acc);
  }
}

extern "C" void kernel_launch(void* const* d_in, const int* in_sizes, int n_in,
                              void* d_out, int out_size, void* d_ws, size_t ws_size,
                              hipStream_t stream) {
  const float* x    = (const float*)d_in[0];
  const float* Wq   = (const float*)d_in[1];
  const float* Wk   = (const float*)d_in[2];
  const float* Wv   = (const float*)d_in[3];
  const float* bg   = (const float*)d_in[4];
  const float* al   = (const float*)d_in[5];
  const float* rW1  = (const float*)d_in[6];
  const float* rb1  = (const float*)d_in[7];
  const float* rW2  = (const float*)d_in[8];
  const float* rb2  = (const float*)d_in[9];
  const float* Wout = (const float*)d_in[10];
  float* out = (float*)d_out;

  // ---- arena (lifetime overlays, ~127 MB) ----
  const size_t MB = 1u << 20;
  char* w = (char*)d_ws;
  u16*   xbf   = (u16*)(w + 0);            // 16 MB [P0-P1]
  u16*   xp2   = (u16*)(w + 16 * MB);      //  8 MB [P0-P1]
  u16*   xp4   = (u16*)(w + 24 * MB);      //  4 MB [P0-P1]
  u16*   xp8   = (u16*)(w + 28 * MB);      //  2 MB [P0-P1]
  float* O     = (float*)(w + 0);          // 32 MB [P4-P5] overlays dead pools
  u16*   Qb    = (u16*)(w + 32 * MB);      // 16 MB [P1-P4]
  u16*   KV    = (u16*)(w + 48 * MB);      // 15 MB [P1-P2]
  u16*   Kp    = (u16*)(w + 48 * MB);      // 7.5MB [P3-P4] overlays dead KV
  u16*   KT    = (u16*)(w + 63 * MB);      // 7.5MB [P2-P3]
  u16*   VT    = (u16*)(w + 70 * MB + 512 * 1024); // 7.5MB [P2-P4]
  float* hid   = (float*)(w + 110 * MB);   //  8 MB [P1-P5]
  u16*   wqT   = (u16*)(w + 118 * MB);     //  2 MB
  u16*   kvT   = (u16*)(w + 120 * MB);     //  4 MB
  u16*   rw1T  = (u16*)(w + 124 * MB);     // 512 KB
  u16*   woutT = (u16*)(w + 124 * MB + 512 * 1024);   // 256 KB
  float* cbuf  = (float*)(w + 124 * MB + 768 * 1024); // 128 KB
  u16*   mixed = (u16*)(w + 125 * MB);     //  2 MB

  auto gemm = [&](const void* A, const void* Bt, void* C, int M, int N, int K,
                  int lda, int ldb, int ldc, long abs_, long bbs, long cbs,
                  int nz, float alpha, bool obf) {
    dim3 g(M / 128, N / 128, nz), blk(256);
    if (obf)
      gemm_bt<true><<<g, blk, 0, stream>>>((const u16*)A, (const u16*)Bt, C, K, lda, ldb, ldc, abs_, bbs, cbs, alpha);
    else
      gemm_bt<false><<<g, blk, 0, stream>>>((const u16*)A, (const u16*)Bt, C, K, lda, ldb, ldc, abs_, bbs, cbs, alpha);
  };

  // P0: fused pooling + weight transposes
  pool_all<<<dim3(1024), dim3(256), 0, stream>>>(x, xbf, xp2, xp4, xp8);
  wq_t<<<dim3(512, 1, 8), dim3(256), 0, stream>>>(Wq, wqT);
  wkv_t<<<dim3(2048, 1, 4), dim3(256), 0, stream>>>(Wk, Wv, kvT);
  t_f32<<<dim3(1024), dim3(256), 0, stream>>>(rW1, rw1T, 1024, 256);
  t_f32<<<dim3(512), dim3(256), 0, stream>>>(Wout, woutT, 128, 1024);

  // P1: projections + router hidden
  gemm(xbf, wqT, Qb, 8192, 1024, 1024, 1024, 1024, 1024, 0, 0, 0, 1, 1.f, true);
  const u16* xps[4] = {xbf, xp2, xp4, xp8};
  const long kvrow[4] = {0, 8192, 12288, 14336};
  const long ktoff[4] = {0, 2097152, 3145728, 3670016};
  for (int g = 0; g < 4; ++g) {
    const int Tk = 4096 >> g;
    gemm(xps[g], kvT + (long)g * 524288, KV + kvrow[g] * 512, 2 * Tk, 512, 1024,
         1024, 1024, 512, 0, 0, 0, 1, 1.f, true);
  }
  gemm(xbf, rw1T, hid, 8192, 256, 1024, 1024, 1024, 256, 0, 0, 0, 1, 1.f, false);

  // P2: K/V transposes + spectral kernel
  for (int g = 0; g < 4; ++g) {
    const int Tk = 4096 >> g;
    tpose_kv<<<dim3(Tk / 32, 4, 8), dim3(256), 0, stream>>>(KV + kvrow[g] * 512, KT + ktoff[g], VT + ktoff[g], Tk);
  }
  irfft_c<<<dim3(16, 8), dim3(256), 0, stream>>>(bg, cbuf);

  // P3: circulant conv (all heads/batches in one launch), iss folded in
  conv_k<<<dim3(32, 1, 16), dim3(256), 0, stream>>>(cbuf, KT, Kp);

  // P4: flash attention (all heads/batches in one launch)
  flash<<<dim3(32, 1, 16), dim3(512), 0, stream>>>(Qb, Kp, VT, O);

  // P5: router softmax + contra-flow mix, then output projection
  router_mix<<<dim3(8192), dim3(256), 0, stream>>>(hid, rb1, rW2, rb2, al, O, mixed);
  gemm(mixed, woutT, out, 8192, 1024, 128, 128, 128, 1024, 0, 0, 0, 1, 1.f, false);
}

// Round 4
// 439.283 us; speedup vs baseline: 3.0205x; 1.0637x over previous
//
#include <hip/hip_runtime.h>
#include <hip/hip_bf16.h>

typedef __attribute__((ext_vector_type(8))) short short8;
typedef __attribute__((ext_vector_type(4))) short short4v;
typedef __attribute__((ext_vector_type(4))) float f32x4;
typedef unsigned short u16;

#define T_ 4096
#define D_ 1024
#define ISS 0.08838834764831845f

__device__ __forceinline__ u16 f2bf(float f) {
  union { float f; unsigned u; } v; v.f = f;
  unsigned r = v.u + 0x7FFFu + ((v.u >> 16) & 1u);
  return (u16)(r >> 16);
}

// ---------- fused 4-way pooling, fp32 -> bf16 ----------
__global__ __launch_bounds__(256) void pool_all(const float* __restrict__ x,
    u16* __restrict__ p1, u16* __restrict__ p2, u16* __restrict__ p4, u16* __restrict__ p8) {
  const int blk = blockIdx.x;
  const int b = blk >> 9, t0 = (blk & 511) << 3;
  const float* src = x + ((long)b * T_ + t0) * D_;
#pragma unroll
  for (int j = 0; j < 4; ++j) {
    const int c = threadIdx.x + j * 256;
    float v[8];
#pragma unroll
    for (int r = 0; r < 8; ++r) v[r] = src[r * D_ + c];
#pragma unroll
    for (int r = 0; r < 8; ++r) p1[((long)b * 4096 + t0 + r) * D_ + c] = f2bf(v[r]);
#pragma unroll
    for (int r = 0; r < 4; ++r)
      p2[((long)b * 2048 + (t0 >> 1) + r) * D_ + c] = f2bf((v[2*r] + v[2*r+1]) * 0.5f);
#pragma unroll
    for (int r = 0; r < 2; ++r)
      p4[((long)b * 1024 + (t0 >> 2) + r) * D_ + c] =
          f2bf((v[4*r] + v[4*r+1] + v[4*r+2] + v[4*r+3]) * 0.25f);
    p8[((long)b * 512 + (t0 >> 3)) * D_ + c] =
        f2bf((v[0]+v[1]+v[2]+v[3]+v[4]+v[5]+v[6]+v[7]) * 0.125f);
  }
}

// ---------- weight transposes (fp32 -> bf16, [K][N] -> [N][K]) ----------
__global__ __launch_bounds__(256) void wq_t(const float* __restrict__ Wq, u16* __restrict__ dst) {
  const int h = blockIdx.z;
  const int idx = blockIdx.x * 256 + threadIdx.x;
  const int c = idx >> 10, k = idx & 1023;
  dst[(long)h * 131072 + idx] = f2bf(Wq[(long)h * 131072 + k * 128 + c]);
}

__global__ __launch_bounds__(256) void wkv_t(const float* __restrict__ Wk, const float* __restrict__ Wv,
                                             u16* __restrict__ dst) {
  const int g = blockIdx.z;
  const int idx = blockIdx.x * 256 + threadIdx.x;
  const int n = idx >> 10, k = idx & 1023;
  const int kv = n >> 8, hh = (n >> 7) & 1, c = n & 127;
  const float* W = kv ? Wv : Wk;
  dst[(long)g * 524288 + idx] = f2bf(W[(long)(2 * g + hh) * 131072 + k * 128 + c]);
}

__global__ __launch_bounds__(256) void t_f32(const float* __restrict__ src, u16* __restrict__ dst,
                                             int R, int C) {
  const int idx = blockIdx.x * 256 + threadIdx.x;
  const int n = idx / R, k = idx - n * R;
  dst[idx] = f2bf(src[(long)k * C + n]);
}

// ---------- bf16 tiled transpose for K,V slices ----------
__global__ __launch_bounds__(256) void tpose_kv(const u16* __restrict__ kvg, u16* __restrict__ KT,
                                                u16* __restrict__ VT, int Tk) {
  __shared__ u16 tile[32][33];
  const int z = blockIdx.z;
  const int b = z & 1, hh = (z >> 1) & 1, kv = z >> 2;
  const u16* src = kvg + (long)b * Tk * 512 + kv * 256 + hh * 128;
  u16* dst = (kv ? VT : KT) + (long)(hh * 2 + b) * 128 * Tk;
  const int r0 = blockIdx.x * 32, c0 = blockIdx.y * 32;
  const int ci = threadIdx.x & 31, ri = threadIdx.x >> 5;
#pragma unroll
  for (int j = 0; j < 4; ++j)
    tile[ri + 8 * j][ci] = src[(long)(r0 + ri + 8 * j) * 512 + c0 + ci];
  __syncthreads();
#pragma unroll
  for (int j = 0; j < 4; ++j)
    dst[(long)(c0 + ri + 8 * j) * Tk + r0 + ci] = tile[ci][ri + 8 * j];
}

// ---------- irfft of gains -> bf16 conv kernel, 4 phase-shifted replicas ----------
// crep[h][p][q] = bf16(c_h[(q+p) & (Tk-1)]),  q in [0, Tk+8), stride 4104 per replica
__global__ __launch_bounds__(256) void irfft_c(const float* __restrict__ bg, u16* __restrict__ crep) {
  const int h = blockIdx.y;
  const int Tk = 4096 >> (h >> 1);
  const int mask = Tk - 1;
  if ((int)(blockIdx.x * 256) >= Tk) return;
  const int nb = (Tk >> 1) + 1;
  __shared__ float ct[4096];
  __shared__ float wm[2049];
  const int tid = threadIdx.x;
  const float w0 = 6.283185307179586f / (float)Tk;
  for (int j = tid; j < Tk; j += 256) ct[j] = cosf(w0 * (float)j);
  for (int m = tid; m < nb; m += 256) {
    int band = (m * 8) / nb; if (band > 7) band = 7;
    const float g = 1.f / (1.f + expf(-bg[h * 8 + band]));
    const float sc = (m == 0 || m == nb - 1) ? 1.f : 2.f;
    wm[m] = g * sc / (float)Tk;
  }
  __syncthreads();
  const int n = blockIdx.x * 256 + tid;
  float acc = 0.f;
  int idx = 0;
  for (int m = 0; m < nb; ++m) {
    acc += wm[m] * ct[idx];
    idx += n;
    if (idx >= Tk) idx -= Tk;
  }
  const u16 bf = f2bf(acc);
  u16* hb = crep + (long)h * 16416;
#pragma unroll
  for (int p = 0; p < 4; ++p) {
    const int q = (n - p) & mask;
    hb[p * 4104 + q] = bf;
    if (q < 8) hb[p * 4104 + q + Tk] = bf;
  }
}

// ---------- async global->LDS ----------
__device__ __forceinline__ void gll16(const void* g, void* l) {
  __builtin_amdgcn_global_load_lds((const __attribute__((address_space(1))) void*)g,
                                   (__attribute__((address_space(3))) void*)l, 16, 0, 0);
}

// ---------- generic bf16 MFMA GEMM (XOR-swizzled LDS): C = alpha*A*Bt^T ----------
template <bool OBF>
__global__ __launch_bounds__(256) void gemm_bt(const u16* __restrict__ A, const u16* __restrict__ Bt,
                                               void* __restrict__ Cv, int K, int lda, int ldb, int ldc,
                                               long abs_, long bbs, long cbs, float alpha) {
  __shared__ u16 lds[2][2][128][32];
  const int tid = threadIdx.x, lane = tid & 63, wid = tid >> 6;
  A += (long)blockIdx.z * abs_;
  Bt += (long)blockIdx.z * bbs;
  const int tm = blockIdx.x * 128, tn = blockIdx.y * 128;
  const int wr = wid >> 1, wc = wid & 1;
  const int srow = lane >> 2;
  const int scol = ((lane & 3) ^ ((lane >> 3) & 3)) * 8;              // swizzled source col
  const u16* ga0 = A + (long)(tm + 32 * wid + srow) * lda + scol;
  const u16* ga1 = ga0 + (long)16 * lda;
  const u16* gb0 = Bt + (long)(tn + 32 * wid + srow) * ldb + scol;
  const u16* gb1 = gb0 + (long)16 * ldb;
  f32x4 acc[4][4] = {};
  const int nk = K >> 5;
  gll16(ga0, &lds[0][0][32 * wid][0]);
  gll16(ga1, &lds[0][0][32 * wid + 16][0]);
  gll16(gb0, &lds[0][1][32 * wid][0]);
  gll16(gb1, &lds[0][1][32 * wid + 16][0]);
  int buf = 0;
  const int fr = lane & 15;
  const int fo2 = (((lane >> 4) & 3) ^ ((lane >> 1) & 3)) * 8;        // swizzled read col
  for (int kt = 0; kt < nk; ++kt) {
    __syncthreads();
    if (kt + 1 < nk) {
      const long ko = (long)(kt + 1) * 32;
      gll16(ga0 + ko, &lds[buf ^ 1][0][32 * wid][0]);
      gll16(ga1 + ko, &lds[buf ^ 1][0][32 * wid + 16][0]);
      gll16(gb0 + ko, &lds[buf ^ 1][1][32 * wid][0]);
      gll16(gb1 + ko, &lds[buf ^ 1][1][32 * wid + 16][0]);
    }
    short8 af[4], bfr[4];
#pragma unroll
    for (int i = 0; i < 4; ++i) {
      af[i]  = *(const short8*)&lds[buf][0][wr * 64 + i * 16 + fr][fo2];
      bfr[i] = *(const short8*)&lds[buf][1][wc * 64 + i * 16 + fr][fo2];
    }
#pragma unroll
    for (int i = 0; i < 4; ++i)
#pragma unroll
      for (int j = 0; j < 4; ++j)
        acc[i][j] = __builtin_amdgcn_mfma_f32_16x16x32_bf16(af[i], bfr[j], acc[i][j], 0, 0, 0);
    buf ^= 1;
  }
  const int er = (lane >> 4) * 4, ec = lane & 15;
  if constexpr (OBF) {
    u16* C = (u16*)Cv + (long)blockIdx.z * cbs;
#pragma unroll
    for (int i = 0; i < 4; ++i)
#pragma unroll
      for (int j = 0; j < 4; ++j)
#pragma unroll
        for (int r = 0; r < 4; ++r)
          C[(long)(tm + wr * 64 + i * 16 + er + r) * ldc + (tn + wc * 64 + j * 16 + ec)] =
              f2bf(acc[i][j][r] * alpha);
  } else {
    float* C = (float*)Cv + (long)blockIdx.z * cbs;
#pragma unroll
    for (int i = 0; i < 4; ++i)
#pragma unroll
      for (int j = 0; j < 4; ++j)
#pragma unroll
        for (int r = 0; r < 4; ++r)
          C[(long)(tm + wr * 64 + i * 16 + er + r) * ldc + (tn + wc * 64 + j * 16 + ec)] =
              acc[i][j][r] * alpha;
  }
}

// ---------- circulant conv GEMM: Kp[m,n] = ISS * sum_k c[(k-m)&mask] * K[k,n] ----------
__global__ __launch_bounds__(256) void conv_k(const u16* __restrict__ crep,
    const u16* __restrict__ KT, u16* __restrict__ Kp) {
  const int z = blockIdx.z, h = z >> 1, b = z & 1, g = h >> 1;
  const int Tk = 4096 >> g, mask = Tk - 1;
  const int tm = blockIdx.x << 7;
  if (tm >= Tk) return;
  __shared__ u16 clds[16416];
  __shared__ u16 blds[2][128][32];
  const int tid = threadIdx.x, lane = tid & 63, wid = tid >> 6;
  const int wr = wid >> 1, wc = wid & 1;
  const int srow = lane >> 2;
  const int scol = ((lane & 3) ^ ((lane >> 3) & 3)) * 8;
  const int fr = lane & 15, fo = (lane >> 4) * 8;
  const int fo2 = (((lane >> 4) & 3) ^ ((lane >> 1) & 3)) * 8;
  {
    const short8* src = (const short8*)(crep + (long)h * 16416);
    short8* dst = (short8*)clds;
    for (int j = tid; j < 2052; j += 256) dst[j] = src[j];
  }
  const long ktofs = 4194304 - (4194304 >> g);
  const u16* Bt = KT + ktofs + (long)((h & 1) * 2 + b) * 128 * Tk;
  u16* out = Kp + ktofs + ((long)(h & 1) << 8) * Tk + ((long)b << 7) * Tk;
  const u16* gb0 = Bt + (long)(32 * wid + srow) * Tk + scol;
  const u16* gb1 = gb0 + (long)16 * Tk;
  f32x4 acc[4][4] = {};
  int base[4];
#pragma unroll
  for (int i = 0; i < 4; ++i) base[i] = (fo - (tm + wr * 64 + i * 16 + fr)) & mask;
  const int p = base[0] & 3;                       // constant phase per lane
  const u16* crow = clds + p * 4104;
  const int nk = Tk >> 5;
  gll16(gb0, &blds[0][32 * wid][0]);
  gll16(gb1, &blds[0][32 * wid + 16][0]);
  int buf = 0;
  for (int kt = 0; kt < nk; ++kt) {
    __syncthreads();
    if (kt + 1 < nk) {
      const long ko = (long)(kt + 1) * 32;
      gll16(gb0 + ko, &blds[buf ^ 1][32 * wid][0]);
      gll16(gb1 + ko, &blds[buf ^ 1][32 * wid + 16][0]);
    }
    short8 af[4], bfr[4];
#pragma unroll
    for (int i = 0; i < 4; ++i) {
      const int a0 = base[i] ^ p;                  // aligned (base - p)
      short4v lo = *(const short4v*)(crow + a0);
      short4v hi = *(const short4v*)(crow + a0 + 4);
      af[i][0] = lo[0]; af[i][1] = lo[1]; af[i][2] = lo[2]; af[i][3] = lo[3];
      af[i][4] = hi[0]; af[i][5] = hi[1]; af[i][6] = hi[2]; af[i][7] = hi[3];
      base[i] = (base[i] + 32) & mask;
      bfr[i] = *(const short8*)&blds[buf][wc * 64 + i * 16 + fr][fo2];
    }
#pragma unroll
    for (int i = 0; i < 4; ++i)
#pragma unroll
      for (int j = 0; j < 4; ++j)
        acc[i][j] = __builtin_amdgcn_mfma_f32_16x16x32_bf16(af[i], bfr[j], acc[i][j], 0, 0, 0);
    buf ^= 1;
  }
  const int er = (lane >> 4) * 4, ec = lane & 15;
#pragma unroll
  for (int i = 0; i < 4; ++i)
#pragma unroll
    for (int j = 0; j < 4; ++j)
#pragma unroll
      for (int r = 0; r < 4; ++r)
        out[(long)(tm + wr * 64 + i * 16 + er + r) * 128 + (wc * 64 + j * 16 + ec)] =
            f2bf(acc[i][j][r] * ISS);
}

// ---------- flash attention: S=Q·Kp^T (pre-scaled), online softmax, O=P·V ----------
__global__ __launch_bounds__(512) void flash(const u16* __restrict__ Qb,
    const u16* __restrict__ Kp, const u16* __restrict__ VT, float* __restrict__ O) {
  const int z0 = blockIdx.z;
  const int z = z0 < 8 ? z0 : (z0 < 12 ? z0 + 4 : z0 - 4);   // pair heavy with light heads per CU
  const int h = z >> 1, b = z & 1, g = h >> 1;
  const int Tk = 4096 >> g;
  const int qtm = blockIdx.x << 7;
  // Plds aliases Klds (K dead after QK^T): 34816 + 32768 = 67.5 KB -> 2 blocks/CU
  __shared__ __align__(16) char smem[34816 + 32768];
  u16 (*Klds)[128][32] = (u16(*)[128][32])smem;
  u16 (*Plds)[136]     = (u16(*)[136])smem;
  u16 (*Vlds)[128][32] = (u16(*)[128][32])(smem + 34816);
  const int tid = threadIdx.x, lane = tid & 63, wid = tid >> 6;
  const int fr = lane & 15, fo = (lane >> 4) * 8;
  const int fo2 = (((lane >> 4) & 3) ^ ((lane >> 1) & 3)) * 8;
  const int srow = lane >> 2;
  const int scol = ((lane & 3) ^ ((lane >> 3) & 3)) * 8;
  const int rbase = (lane >> 4) * 4;
  const u16* qptr = Qb + ((long)(b * 4096 + qtm + wid * 16 + fr) * 1024 + h * 128);
  short8 aq[4];
#pragma unroll
  for (int kk = 0; kk < 4; ++kk) aq[kk] = *(const short8*)(qptr + kk * 32 + fo);
  const long ktofs = 4194304 - (4194304 >> g);
  const u16* kbase = Kp + ktofs + ((long)(h & 1) << 8) * Tk + ((long)b << 7) * Tk;
  const u16* vbase = VT + ktofs + (long)((h & 1) * 2 + b) * 128 * Tk;
  f32x4 acc[8] = {};
  float mr[4], lr[4];
#pragma unroll
  for (int r = 0; r < 4; ++r) { mr[r] = -3e38f; lr[r] = 0.f; }
  const int nt = Tk >> 7;
  const u16* vsl = vbase + (long)(wid * 16 + srow) * Tk + scol;
  for (int kt = 0; kt < nt; ++kt) {
    const u16* ksl = kbase + (long)(kt * 128 + wid * 16 + srow) * 128 + scol;
#pragma unroll
    for (int kk = 0; kk < 4; ++kk) gll16(ksl + kk * 32, &Klds[kk][wid * 16][0]);
    __syncthreads();                                   // K staged
#pragma unroll
    for (int kk = 0; kk < 4; ++kk) gll16(vsl + kt * 128 + kk * 32, &Vlds[kk][wid * 16][0]);
    // QK^T
    f32x4 sa[8] = {};
#pragma unroll
    for (int kk = 0; kk < 4; ++kk)
#pragma unroll
      for (int j = 0; j < 8; ++j) {
        short8 bk = *(const short8*)&Klds[kk][j * 16 + fr][fo2];
        sa[j] = __builtin_amdgcn_mfma_f32_16x16x32_bf16(aq[kk], bk, sa[j], 0, 0, 0);
      }
    // online softmax
    float tmax[4];
#pragma unroll
    for (int r = 0; r < 4; ++r) tmax[r] = sa[0][r];
#pragma unroll
    for (int j = 1; j < 8; ++j)
#pragma unroll
      for (int r = 0; r < 4; ++r) tmax[r] = fmaxf(tmax[r], sa[j][r]);
#pragma unroll
    for (int r = 0; r < 4; ++r) {
      tmax[r] = fmaxf(tmax[r], __shfl_xor(tmax[r], 1));
      tmax[r] = fmaxf(tmax[r], __shfl_xor(tmax[r], 2));
      tmax[r] = fmaxf(tmax[r], __shfl_xor(tmax[r], 4));
      tmax[r] = fmaxf(tmax[r], __shfl_xor(tmax[r], 8));
    }
    float mn[4], al[4], ps[4];
#pragma unroll
    for (int r = 0; r < 4; ++r) {
      mn[r] = fmaxf(mr[r], tmax[r]);
      al[r] = __expf(mr[r] - mn[r]);
      ps[r] = 0.f;
    }
#pragma unroll
    for (int j = 0; j < 8; ++j)
#pragma unroll
      for (int r = 0; r < 4; ++r) {
        float pp = __expf(sa[j][r] - mn[r]);
        sa[j][r] = pp;
        ps[r] += pp;
      }
#pragma unroll
    for (int r = 0; r < 4; ++r) {
      ps[r] += __shfl_xor(ps[r], 1);
      ps[r] += __shfl_xor(ps[r], 2);
      ps[r] += __shfl_xor(ps[r], 4);
      ps[r] += __shfl_xor(ps[r], 8);
      lr[r] = lr[r] * al[r] + ps[r];
      mr[r] = mn[r];
    }
#pragma unroll
    for (int jd = 0; jd < 8; ++jd)
#pragma unroll
      for (int r = 0; r < 4; ++r) acc[jd][r] *= al[r];
    __syncthreads();                                   // all waves done reading Klds
#pragma unroll
    for (int j = 0; j < 8; ++j)
#pragma unroll
      for (int r = 0; r < 4; ++r)
        Plds[wid * 16 + rbase + r][j * 16 + (lane & 15)] = f2bf(sa[j][r]);
    __syncthreads();                                   // P visible, V arrived
    // PV
#pragma unroll
    for (int kk = 0; kk < 4; ++kk) {
      short8 ap = *(const short8*)&Plds[wid * 16 + fr][kk * 32 + fo];
#pragma unroll
      for (int jd = 0; jd < 8; ++jd) {
        short8 bv = *(const short8*)&Vlds[kk][jd * 16 + fr][fo2];
        acc[jd] = __builtin_amdgcn_mfma_f32_16x16x32_bf16(ap, bv, acc[jd], 0, 0, 0);
      }
    }
    __syncthreads();                                   // P/V reads done before next stage
  }
  float inv[4];
#pragma unroll
  for (int r = 0; r < 4; ++r) inv[r] = 1.f / lr[r];
#pragma unroll
  for (int jd = 0; jd < 8; ++jd)
#pragma unroll
    for (int r = 0; r < 4; ++r) {
      const int row = qtm + wid * 16 + rbase + r;
      O[((long)(b * 4096 + row) * 8 + h) * 128 + jd * 16 + (lane & 15)] = acc[jd][r] * inv[r];
    }
}

// ---------- fused router MLP tail + contra-flow + head mixing ----------
__global__ __launch_bounds__(256) void router_mix(const float* __restrict__ hid,
    const float* __restrict__ rb1, const float* __restrict__ rW2, const float* __restrict__ rb2,
    const float* __restrict__ al, const float* __restrict__ O, u16* __restrict__ mixed) {
  const int tok = blockIdx.x;
  const int b = tok >> 12, t = tok & 4095;
  const int tid = threadIdx.x;
  __shared__ float lred[4][8];
  __shared__ float wgt[8];
  __shared__ float ta[8];
  const float hv = fmaxf(hid[(long)tok * 256 + tid] + rb1[tid], 0.f);
  const float4* w4 = (const float4*)(rW2 + tid * 8);
  const float4 wa = w4[0], wb = w4[1];
  float part[8] = {hv * wa.x, hv * wa.y, hv * wa.z, hv * wa.w,
                   hv * wb.x, hv * wb.y, hv * wb.z, hv * wb.w};
#pragma unroll
  for (int h = 0; h < 8; ++h) {
    float v = part[h];
#pragma unroll
    for (int o = 1; o < 64; o <<= 1) v += __shfl_xor(v, o);
    if ((tid & 63) == 0) lred[tid >> 6][h] = v;
  }
  __syncthreads();
  if (tid < 8) ta[tid] = tanhf(al[tid]);
  if (tid == 0) {
    float lg[8], m = -1e30f;
#pragma unroll
    for (int h = 0; h < 8; ++h) {
      lg[h] = lred[0][h] + lred[1][h] + lred[2][h] + lred[3][h] + rb2[h];
      m = fmaxf(m, lg[h]);
    }
    float s = 0.f;
#pragma unroll
    for (int h = 0; h < 8; ++h) { lg[h] = __expf(lg[h] - m); s += lg[h]; }
    const float inv = 1.f / s;
#pragma unroll
    for (int h = 0; h < 8; ++h) wgt[h] = lg[h] * inv;
  }
  __syncthreads();
  if (tid < 128) {
    const long base = (long)tok * 1024 + tid;
    const long rbase = ((long)b * 4096 + (4095 - t)) * 1024 + tid;
    float acc = 0.f;
#pragma unroll
    for (int h = 0; h < 8; ++h)
      acc += wgt[h] * (O[base + h * 128] + ta[h] * O[rbase + h * 128]);
    mixed[(long)tok * 128 + tid] = f2bf(acc);
  }
}

extern "C" void kernel_launch(void* const* d_in, const int* in_sizes, int n_in,
                              void* d_out, int out_size, void* d_ws, size_t ws_size,
                              hipStream_t stream) {
  const float* x    = (const float*)d_in[0];
  const float* Wq   = (const float*)d_in[1];
  const float* Wk   = (const float*)d_in[2];
  const float* Wv   = (const float*)d_in[3];
  const float* bg   = (const float*)d_in[4];
  const float* al   = (const float*)d_in[5];
  const float* rW1  = (const float*)d_in[6];
  const float* rb1  = (const float*)d_in[7];
  const float* rW2  = (const float*)d_in[8];
  const float* rb2  = (const float*)d_in[9];
  const float* Wout = (const float*)d_in[10];
  float* out = (float*)d_out;

  // ---- arena (lifetime overlays, ~95.5 MB) ----
  const size_t MB = 1u << 20;
  char* w = (char*)d_ws;
  u16*   xbf   = (u16*)(w + 0);            // 16 MB [P0-P1]
  u16*   xp2   = (u16*)(w + 16 * MB);      //  8 MB [P0-P1]
  u16*   xp4   = (u16*)(w + 24 * MB);      //  4 MB [P0-P1]
  u16*   xp8   = (u16*)(w + 28 * MB);      //  2 MB [P0-P1]
  float* O     = (float*)(w + 0);          // 32 MB [P4-P5] overlays dead pools
  u16*   Qb    = (u16*)(w + 32 * MB);      // 16 MB [P1-P4]
  u16*   KV    = (u16*)(w + 48 * MB);      // 15 MB [P1-P2]
  u16*   Kp    = (u16*)(w + 48 * MB);      // 7.5MB [P3-P4] overlays dead KV
  u16*   KT    = (u16*)(w + 63 * MB);      // 7.5MB [P2-P3]
  u16*   VT    = (u16*)(w + 70 * MB + 512 * 1024); // 7.5MB [P2-P4]
  float* hid   = (float*)(w + 78 * MB);    //  8 MB [P1-P5]
  u16*   wqT   = (u16*)(w + 86 * MB);      //  2 MB
  u16*   kvT   = (u16*)(w + 88 * MB);      //  4 MB
  u16*   rw1T  = (u16*)(w + 92 * MB);      // 512 KB
  u16*   woutT = (u16*)(w + 92 * MB + 512 * 1024);   // 256 KB
  u16*   crep  = (u16*)(w + 92 * MB + 768 * 1024);   // 257 KB
  u16*   mixed = (u16*)(w + 93 * MB + 512 * 1024);   //  2 MB

  auto gemm = [&](const void* A, const void* Bt, void* C, int M, int N, int K,
                  int lda, int ldb, int ldc, long abs_, long bbs, long cbs,
                  int nz, float alpha, bool obf) {
    dim3 g(M / 128, N / 128, nz), blk(256);
    if (obf)
      gemm_bt<true><<<g, blk, 0, stream>>>((const u16*)A, (const u16*)Bt, C, K, lda, ldb, ldc, abs_, bbs, cbs, alpha);
    else
      gemm_bt<false><<<g, blk, 0, stream>>>((const u16*)A, (const u16*)Bt, C, K, lda, ldb, ldc, abs_, bbs, cbs, alpha);
  };

  // P0: fused pooling + weight transposes
  pool_all<<<dim3(1024), dim3(256), 0, stream>>>(x, xbf, xp2, xp4, xp8);
  wq_t<<<dim3(512, 1, 8), dim3(256), 0, stream>>>(Wq, wqT);
  wkv_t<<<dim3(2048, 1, 4), dim3(256), 0, stream>>>(Wk, Wv, kvT);
  t_f32<<<dim3(1024), dim3(256), 0, stream>>>(rW1, rw1T, 1024, 256);
  t_f32<<<dim3(512), dim3(256), 0, stream>>>(Wout, woutT, 128, 1024);

  // P1: projections + router hidden
  gemm(xbf, wqT, Qb, 8192, 1024, 1024, 1024, 1024, 1024, 0, 0, 0, 1, 1.f, true);
  const u16* xps[4] = {xbf, xp2, xp4, xp8};
  const long kvrow[4] = {0, 8192, 12288, 14336};
  const long ktoff[4] = {0, 2097152, 3145728, 3670016};
  for (int g = 0; g < 4; ++g) {
    const int Tk = 4096 >> g;
    gemm(xps[g], kvT + (long)g * 524288, KV + kvrow[g] * 512, 2 * Tk, 512, 1024,
         1024, 1024, 512, 0, 0, 0, 1, 1.f, true);
  }
  gemm(xbf, rw1T, hid, 8192, 256, 1024, 1024, 1024, 256, 0, 0, 0, 1, 1.f, false);

  // P2: K/V transposes + spectral kernel replicas
  for (int g = 0; g < 4; ++g) {
    const int Tk = 4096 >> g;
    tpose_kv<<<dim3(Tk / 32, 4, 8), dim3(256), 0, stream>>>(KV + kvrow[g] * 512, KT + ktoff[g], VT + ktoff[g], Tk);
  }
  irfft_c<<<dim3(16, 8), dim3(256), 0, stream>>>(bg, crep);

  // P3: circulant conv (all heads/batches), iss folded in
  conv_k<<<dim3(32, 1, 16), dim3(256), 0, stream>>>(crep, KT, Kp);

  // P4: flash attention (all heads/batches)
  flash<<<dim3(32, 1, 16), dim3(512), 0, stream>>>(Qb, Kp, VT, O);

  // P5: router softmax + contra-flow mix, then output projection
  router_mix<<<dim3(8192), dim3(256), 0, stream>>>(hid, rb1, rW2, rb2, al, O, mixed);
  gemm(mixed, woutT, out, 8192, 1024, 128, 128, 128, 1024, 0, 0, 0, 1, 1.f, false);
}

// Round 5
// 438.546 us; speedup vs baseline: 3.0255x; 1.0017x over previous
//
#include <hip/hip_runtime.h>
#include <hip/hip_bf16.h>

typedef __attribute__((ext_vector_type(8))) short short8;
typedef __attribute__((ext_vector_type(4))) short short4v;
typedef __attribute__((ext_vector_type(4))) float f32x4;
typedef unsigned short u16;

#define T_ 4096
#define D_ 1024
#define ISSL2E (0.08838834764831845f * 1.4426950408889634f)   // 1/sqrt(128) * log2(e)

__device__ __forceinline__ u16 f2bf(float f) {
  union { float f; unsigned u; } v; v.f = f;
  unsigned r = v.u + 0x7FFFu + ((v.u >> 16) & 1u);
  return (u16)(r >> 16);
}

// ---------- fused 4-way pooling, fp32 -> bf16 ----------
__global__ __launch_bounds__(256) void pool_all(const float* __restrict__ x,
    u16* __restrict__ p1, u16* __restrict__ p2, u16* __restrict__ p4, u16* __restrict__ p8) {
  const int blk = blockIdx.x;
  const int b = blk >> 9, t0 = (blk & 511) << 3;
  const float* src = x + ((long)b * T_ + t0) * D_;
#pragma unroll
  for (int j = 0; j < 4; ++j) {
    const int c = threadIdx.x + j * 256;
    float v[8];
#pragma unroll
    for (int r = 0; r < 8; ++r) v[r] = src[r * D_ + c];
#pragma unroll
    for (int r = 0; r < 8; ++r) p1[((long)b * 4096 + t0 + r) * D_ + c] = f2bf(v[r]);
#pragma unroll
    for (int r = 0; r < 4; ++r)
      p2[((long)b * 2048 + (t0 >> 1) + r) * D_ + c] = f2bf((v[2*r] + v[2*r+1]) * 0.5f);
#pragma unroll
    for (int r = 0; r < 2; ++r)
      p4[((long)b * 1024 + (t0 >> 2) + r) * D_ + c] =
          f2bf((v[4*r] + v[4*r+1] + v[4*r+2] + v[4*r+3]) * 0.25f);
    p8[((long)b * 512 + (t0 >> 3)) * D_ + c] =
        f2bf((v[0]+v[1]+v[2]+v[3]+v[4]+v[5]+v[6]+v[7]) * 0.125f);
  }
}

// ---------- weight transposes (fp32 -> bf16, [K][N] -> [N][K]) ----------
__global__ __launch_bounds__(256) void wq_t(const float* __restrict__ Wq, u16* __restrict__ dst) {
  const int h = blockIdx.z;
  const int idx = blockIdx.x * 256 + threadIdx.x;
  const int c = idx >> 10, k = idx & 1023;
  dst[(long)h * 131072 + idx] = f2bf(Wq[(long)h * 131072 + k * 128 + c]);
}

__global__ __launch_bounds__(256) void wkv_t(const float* __restrict__ Wk, const float* __restrict__ Wv,
                                             u16* __restrict__ dst) {
  const int g = blockIdx.z;
  const int idx = blockIdx.x * 256 + threadIdx.x;
  const int n = idx >> 10, k = idx & 1023;
  const int kv = n >> 8, hh = (n >> 7) & 1, c = n & 127;
  const float* W = kv ? Wv : Wk;
  dst[(long)g * 524288 + idx] = f2bf(W[(long)(2 * g + hh) * 131072 + k * 128 + c]);
}

__global__ __launch_bounds__(256) void t_f32(const float* __restrict__ src, u16* __restrict__ dst,
                                             int R, int C) {
  const int idx = blockIdx.x * 256 + threadIdx.x;
  const int n = idx / R, k = idx - n * R;
  dst[idx] = f2bf(src[(long)k * C + n]);
}

// ---------- bf16 tiled transpose for K,V slices ----------
__global__ __launch_bounds__(256) void tpose_kv(const u16* __restrict__ kvg, u16* __restrict__ KT,
                                                u16* __restrict__ VT, int Tk) {
  __shared__ u16 tile[32][33];
  const int z = blockIdx.z;
  const int b = z & 1, hh = (z >> 1) & 1, kv = z >> 2;
  const u16* src = kvg + (long)b * Tk * 512 + kv * 256 + hh * 128;
  u16* dst = (kv ? VT : KT) + (long)(hh * 2 + b) * 128 * Tk;
  const int r0 = blockIdx.x * 32, c0 = blockIdx.y * 32;
  const int ci = threadIdx.x & 31, ri = threadIdx.x >> 5;
#pragma unroll
  for (int j = 0; j < 4; ++j)
    tile[ri + 8 * j][ci] = src[(long)(r0 + ri + 8 * j) * 512 + c0 + ci];
  __syncthreads();
#pragma unroll
  for (int j = 0; j < 4; ++j)
    dst[(long)(c0 + ri + 8 * j) * Tk + r0 + ci] = tile[ci][ri + 8 * j];
}

// ---------- irfft of gains -> bf16 conv kernel, 4 phase-shifted replicas ----------
__global__ __launch_bounds__(256) void irfft_c(const float* __restrict__ bg, u16* __restrict__ crep) {
  const int h = blockIdx.y;
  const int Tk = 4096 >> (h >> 1);
  const int mask = Tk - 1;
  if ((int)(blockIdx.x * 256) >= Tk) return;
  const int nb = (Tk >> 1) + 1;
  __shared__ float ct[4096];
  __shared__ float wm[2049];
  const int tid = threadIdx.x;
  const float w0 = 6.283185307179586f / (float)Tk;
  for (int j = tid; j < Tk; j += 256) ct[j] = cosf(w0 * (float)j);
  for (int m = tid; m < nb; m += 256) {
    int band = (m * 8) / nb; if (band > 7) band = 7;
    const float g = 1.f / (1.f + expf(-bg[h * 8 + band]));
    const float sc = (m == 0 || m == nb - 1) ? 1.f : 2.f;
    wm[m] = g * sc / (float)Tk;
  }
  __syncthreads();
  const int n = blockIdx.x * 256 + tid;
  float acc = 0.f;
  int idx = 0;
  for (int m = 0; m < nb; ++m) {
    acc += wm[m] * ct[idx];
    idx += n;
    if (idx >= Tk) idx -= Tk;
  }
  const u16 bf = f2bf(acc);
  u16* hb = crep + (long)h * 16416;
#pragma unroll
  for (int p = 0; p < 4; ++p) {
    const int q = (n - p) & mask;
    hb[p * 4104 + q] = bf;
    if (q < 8) hb[p * 4104 + q + Tk] = bf;
  }
}

// ---------- async global->LDS ----------
__device__ __forceinline__ void gll16(const void* g, void* l) {
  __builtin_amdgcn_global_load_lds((const __attribute__((address_space(1))) void*)g,
                                   (__attribute__((address_space(3))) void*)l, 16, 0, 0);
}

// ---------- generic bf16 MFMA GEMM (XOR-swizzled LDS): C = alpha*A*Bt^T ----------
template <bool OBF>
__global__ __launch_bounds__(256) void gemm_bt(const u16* __restrict__ A, const u16* __restrict__ Bt,
                                               void* __restrict__ Cv, int K, int lda, int ldb, int ldc,
                                               long abs_, long bbs, long cbs, float alpha) {
  __shared__ u16 lds[2][2][128][32];
  const int tid = threadIdx.x, lane = tid & 63, wid = tid >> 6;
  A += (long)blockIdx.z * abs_;
  Bt += (long)blockIdx.z * bbs;
  const int tm = blockIdx.x * 128, tn = blockIdx.y * 128;
  const int wr = wid >> 1, wc = wid & 1;
  const int srow = lane >> 2;
  const int scol = ((lane & 3) ^ ((lane >> 3) & 3)) * 8;
  const u16* ga0 = A + (long)(tm + 32 * wid + srow) * lda + scol;
  const u16* ga1 = ga0 + (long)16 * lda;
  const u16* gb0 = Bt + (long)(tn + 32 * wid + srow) * ldb + scol;
  const u16* gb1 = gb0 + (long)16 * ldb;
  f32x4 acc[4][4] = {};
  const int nk = K >> 5;
  gll16(ga0, &lds[0][0][32 * wid][0]);
  gll16(ga1, &lds[0][0][32 * wid + 16][0]);
  gll16(gb0, &lds[0][1][32 * wid][0]);
  gll16(gb1, &lds[0][1][32 * wid + 16][0]);
  int buf = 0;
  const int fr = lane & 15;
  const int fo2 = (((lane >> 4) & 3) ^ ((lane >> 1) & 3)) * 8;
  for (int kt = 0; kt < nk; ++kt) {
    __syncthreads();
    if (kt + 1 < nk) {
      const long ko = (long)(kt + 1) * 32;
      gll16(ga0 + ko, &lds[buf ^ 1][0][32 * wid][0]);
      gll16(ga1 + ko, &lds[buf ^ 1][0][32 * wid + 16][0]);
      gll16(gb0 + ko, &lds[buf ^ 1][1][32 * wid][0]);
      gll16(gb1 + ko, &lds[buf ^ 1][1][32 * wid + 16][0]);
    }
    short8 af[4], bfr[4];
#pragma unroll
    for (int i = 0; i < 4; ++i) {
      af[i]  = *(const short8*)&lds[buf][0][wr * 64 + i * 16 + fr][fo2];
      bfr[i] = *(const short8*)&lds[buf][1][wc * 64 + i * 16 + fr][fo2];
    }
#pragma unroll
    for (int i = 0; i < 4; ++i)
#pragma unroll
      for (int j = 0; j < 4; ++j)
        acc[i][j] = __builtin_amdgcn_mfma_f32_16x16x32_bf16(af[i], bfr[j], acc[i][j], 0, 0, 0);
    buf ^= 1;
  }
  const int er = (lane >> 4) * 4, ec = lane & 15;
  if constexpr (OBF) {
    u16* C = (u16*)Cv + (long)blockIdx.z * cbs;
#pragma unroll
    for (int i = 0; i < 4; ++i)
#pragma unroll
      for (int j = 0; j < 4; ++j)
#pragma unroll
        for (int r = 0; r < 4; ++r)
          C[(long)(tm + wr * 64 + i * 16 + er + r) * ldc + (tn + wc * 64 + j * 16 + ec)] =
              f2bf(acc[i][j][r] * alpha);
  } else {
    float* C = (float*)Cv + (long)blockIdx.z * cbs;
#pragma unroll
    for (int i = 0; i < 4; ++i)
#pragma unroll
      for (int j = 0; j < 4; ++j)
#pragma unroll
        for (int r = 0; r < 4; ++r)
          C[(long)(tm + wr * 64 + i * 16 + er + r) * ldc + (tn + wc * 64 + j * 16 + ec)] =
              acc[i][j][r] * alpha;
  }
}

// ---------- circulant conv GEMM: Kp[m,n] = ISSL2E * sum_k c[(k-m)&mask] * K[k,n] ----------
__global__ __launch_bounds__(256) void conv_k(const u16* __restrict__ crep,
    const u16* __restrict__ KT, u16* __restrict__ Kp) {
  const int z = blockIdx.z, h = z >> 1, b = z & 1, g = h >> 1;
  const int Tk = 4096 >> g, mask = Tk - 1;
  const int tm = blockIdx.x << 7;
  if (tm >= Tk) return;
  __shared__ u16 clds[16416];
  __shared__ u16 blds[2][128][32];
  const int tid = threadIdx.x, lane = tid & 63, wid = tid >> 6;
  const int wr = wid >> 1, wc = wid & 1;
  const int srow = lane >> 2;
  const int scol = ((lane & 3) ^ ((lane >> 3) & 3)) * 8;
  const int fr = lane & 15, fo = (lane >> 4) * 8;
  const int fo2 = (((lane >> 4) & 3) ^ ((lane >> 1) & 3)) * 8;
  {
    const short8* src = (const short8*)(crep + (long)h * 16416);
    short8* dst = (short8*)clds;
    for (int j = tid; j < 2052; j += 256) dst[j] = src[j];
  }
  const long ktofs = 4194304 - (4194304 >> g);
  const u16* Bt = KT + ktofs + (long)((h & 1) * 2 + b) * 128 * Tk;
  u16* out = Kp + ktofs + ((long)(h & 1) << 8) * Tk + ((long)b << 7) * Tk;
  const u16* gb0 = Bt + (long)(32 * wid + srow) * Tk + scol;
  const u16* gb1 = gb0 + (long)16 * Tk;
  f32x4 acc[4][4] = {};
  int base[4];
#pragma unroll
  for (int i = 0; i < 4; ++i) base[i] = (fo - (tm + wr * 64 + i * 16 + fr)) & mask;
  const int p = base[0] & 3;
  const u16* crow = clds + p * 4104;
  const int nk = Tk >> 5;
  gll16(gb0, &blds[0][32 * wid][0]);
  gll16(gb1, &blds[0][32 * wid + 16][0]);
  int buf = 0;
  for (int kt = 0; kt < nk; ++kt) {
    __syncthreads();
    if (kt + 1 < nk) {
      const long ko = (long)(kt + 1) * 32;
      gll16(gb0 + ko, &blds[buf ^ 1][32 * wid][0]);
      gll16(gb1 + ko, &blds[buf ^ 1][32 * wid + 16][0]);
    }
    short8 af[4], bfr[4];
#pragma unroll
    for (int i = 0; i < 4; ++i) {
      const int a0 = base[i] ^ p;
      short4v lo = *(const short4v*)(crow + a0);
      short4v hi = *(const short4v*)(crow + a0 + 4);
      af[i][0] = lo[0]; af[i][1] = lo[1]; af[i][2] = lo[2]; af[i][3] = lo[3];
      af[i][4] = hi[0]; af[i][5] = hi[1]; af[i][6] = hi[2]; af[i][7] = hi[3];
      base[i] = (base[i] + 32) & mask;
      bfr[i] = *(const short8*)&blds[buf][wc * 64 + i * 16 + fr][fo2];
    }
#pragma unroll
    for (int i = 0; i < 4; ++i)
#pragma unroll
      for (int j = 0; j < 4; ++j)
        acc[i][j] = __builtin_amdgcn_mfma_f32_16x16x32_bf16(af[i], bfr[j], acc[i][j], 0, 0, 0);
    buf ^= 1;
  }
  const int er = (lane >> 4) * 4, ec = lane & 15;
#pragma unroll
  for (int i = 0; i < 4; ++i)
#pragma unroll
    for (int j = 0; j < 4; ++j)
#pragma unroll
      for (int r = 0; r < 4; ++r)
        out[(long)(tm + wr * 64 + i * 16 + er + r) * 128 + (wc * 64 + j * 16 + ec)] =
            f2bf(acc[i][j][r] * ISSL2E);
}

// ---------- flash attention, XCD-pinned, counted-vmcnt pipeline ----------
// scores are pre-scaled to exp2 domain (ISSL2E folded into Kp)
__global__ __launch_bounds__(512) void flash(const u16* __restrict__ Qb,
    const u16* __restrict__ Kp, const u16* __restrict__ VT, float* __restrict__ O) {
  const int wg = blockIdx.x;
  const int xcd = wg & 7, slot = wg >> 3;
  int h, b;
  if (xcd < 4) {
    if (slot >= 32) return;          // heavy XCDs: one (h,b) job, 32 q-tiles
    h = xcd >> 1; b = xcd & 1;       // h in {0,1}, Tk=4096
  } else {
    const int set = xcd - 4, lvl = slot >> 5;   // lvl 0,1,2 -> Tk 2048,1024,512
    h = 2 + lvl * 2 + (set >> 1); b = set & 1;
  }
  const int qtile = slot & 31;
  const int g = h >> 1;
  const int Tk = 4096 >> g;
  const int qtm = qtile << 7;
  const int nt = Tk >> 7;

  __shared__ u16 Kl[2][4][128][32];   // 64 KB double-buffered K
  __shared__ u16 Vl[4][128][32];      // 32 KB
  __shared__ u16 Pl[128][136];        // 34 KB, wave-private strips

  const int tid = threadIdx.x, lane = tid & 63, wid = tid >> 6;
  const int fr = lane & 15, fo = (lane >> 4) * 8;
  const int fo2 = (((lane >> 4) & 3) ^ ((lane >> 1) & 3)) * 8;
  const int srow = lane >> 2;
  const int scol = ((lane & 3) ^ ((lane >> 3) & 3)) * 8;
  const int rbase = (lane >> 4) * 4;

  const u16* qptr = Qb + ((long)(b * 4096 + qtm + wid * 16 + fr) * 1024 + h * 128);
  short8 aq[4];
#pragma unroll
  for (int kk = 0; kk < 4; ++kk) aq[kk] = *(const short8*)(qptr + kk * 32 + fo);
  const long ktofs = 4194304 - (4194304 >> g);
  const u16* kbase = Kp + ktofs + ((long)(h & 1) << 8) * Tk + ((long)b << 7) * Tk;
  const u16* vbase = VT + ktofs + (long)((h & 1) * 2 + b) * 128 * Tk;
  const u16* ksl0 = kbase + (long)(wid * 16 + srow) * 128 + scol;
  const u16* vsl  = vbase + (long)(wid * 16 + srow) * Tk + scol;

  f32x4 acc[8] = {};
  float mr[4], lr[4];
#pragma unroll
  for (int r = 0; r < 4; ++r) { mr[r] = -3e38f; lr[r] = 0.f; }

  // prologue: stage K(0)
#pragma unroll
  for (int kk = 0; kk < 4; ++kk) gll16(ksl0 + kk * 32, &Kl[0][kk][wid * 16][0]);
  int cur = 0;
  for (int kt = 0; kt < nt; ++kt) {
    asm volatile("s_waitcnt vmcnt(0)" ::: "memory");   // own K(kt) chunks done (also: all PV reads of Vl are behind the barrier)
    __builtin_amdgcn_sched_barrier(0);
    __builtin_amdgcn_s_barrier();                      // K(kt) visible block-wide; Vl free
    __builtin_amdgcn_sched_barrier(0);
    // issue V(kt) then K(kt+1): V latency hides under QK+softmax, K under everything
#pragma unroll
    for (int kk = 0; kk < 4; ++kk) gll16(vsl + (long)kt * 128 + kk * 32, &Vl[kk][wid * 16][0]);
    const int nxt = (kt + 1 < nt) ? kt + 1 : 0;        // tail: harmless reload keeps counts uniform
    const u16* ka = ksl0 + (long)nxt * 16384;
#pragma unroll
    for (int kk = 0; kk < 4; ++kk) gll16(ka + kk * 32, &Kl[cur ^ 1][kk][wid * 16][0]);
    // QK^T from Kl[cur]
    f32x4 sa[8] = {};
#pragma unroll
    for (int kk = 0; kk < 4; ++kk)
#pragma unroll
      for (int j = 0; j < 8; ++j) {
        short8 bk = *(const short8*)&Kl[cur][kk][j * 16 + fr][fo2];
        sa[j] = __builtin_amdgcn_mfma_f32_16x16x32_bf16(aq[kk], bk, sa[j], 0, 0, 0);
      }
    // online softmax (exp2 domain), deferred rescale
    float tmax[4];
#pragma unroll
    for (int r = 0; r < 4; ++r) tmax[r] = sa[0][r];
#pragma unroll
    for (int j = 1; j < 8; ++j)
#pragma unroll
      for (int r = 0; r < 4; ++r) tmax[r] = fmaxf(tmax[r], sa[j][r]);
#pragma unroll
    for (int r = 0; r < 4; ++r) {
      tmax[r] = fmaxf(tmax[r], __shfl_xor(tmax[r], 1));
      tmax[r] = fmaxf(tmax[r], __shfl_xor(tmax[r], 2));
      tmax[r] = fmaxf(tmax[r], __shfl_xor(tmax[r], 4));
      tmax[r] = fmaxf(tmax[r], __shfl_xor(tmax[r], 8));
    }
    const bool grow = (tmax[0] > mr[0]) | (tmax[1] > mr[1]) |
                      (tmax[2] > mr[2]) | (tmax[3] > mr[3]);
    if (__any((int)grow)) {
      float av[4];
#pragma unroll
      for (int r = 0; r < 4; ++r) {
        const float mn = fmaxf(mr[r], tmax[r]);
        av[r] = exp2f(mr[r] - mn);
        lr[r] *= av[r];
        mr[r] = mn;
      }
#pragma unroll
      for (int jd = 0; jd < 8; ++jd)
#pragma unroll
        for (int r = 0; r < 4; ++r) acc[jd][r] *= av[r];
    }
    float ps[4] = {0.f, 0.f, 0.f, 0.f};
#pragma unroll
    for (int j = 0; j < 8; ++j)
#pragma unroll
      for (int r = 0; r < 4; ++r) {
        const float p = exp2f(sa[j][r] - mr[r]);
        sa[j][r] = p;
        ps[r] += p;
      }
#pragma unroll
    for (int r = 0; r < 4; ++r) {
      ps[r] += __shfl_xor(ps[r], 1);
      ps[r] += __shfl_xor(ps[r], 2);
      ps[r] += __shfl_xor(ps[r], 4);
      ps[r] += __shfl_xor(ps[r], 8);
      lr[r] += ps[r];
    }
    // P write: wave-private strip, no barrier needed
#pragma unroll
    for (int j = 0; j < 8; ++j)
#pragma unroll
      for (int r = 0; r < 4; ++r)
        Pl[wid * 16 + rbase + r][j * 16 + fr] = f2bf(sa[j][r]);
    asm volatile("s_waitcnt vmcnt(4)" ::: "memory");   // V(kt) done; K(kt+1) still in flight
    __builtin_amdgcn_sched_barrier(0);
    __builtin_amdgcn_s_barrier();                      // V visible block-wide
    __builtin_amdgcn_sched_barrier(0);
    // PV: A = own P strip, B = V
#pragma unroll
    for (int kk = 0; kk < 4; ++kk) {
      short8 ap = *(const short8*)&Pl[wid * 16 + fr][kk * 32 + fo];
#pragma unroll
      for (int jd = 0; jd < 8; ++jd) {
        short8 bv = *(const short8*)&Vl[kk][jd * 16 + fr][fo2];
        acc[jd] = __builtin_amdgcn_mfma_f32_16x16x32_bf16(ap, bv, acc[jd], 0, 0, 0);
      }
    }
    cur ^= 1;
  }
  float inv[4];
#pragma unroll
  for (int r = 0; r < 4; ++r) inv[r] = 1.f / lr[r];
#pragma unroll
  for (int jd = 0; jd < 8; ++jd)
#pragma unroll
    for (int r = 0; r < 4; ++r) {
      const int row = qtm + wid * 16 + rbase + r;
      O[((long)(b * 4096 + row) * 8 + h) * 128 + jd * 16 + fr] = acc[jd][r] * inv[r];
    }
}

// ---------- fused router MLP tail + contra-flow + head mixing ----------
__global__ __launch_bounds__(256) void router_mix(const float* __restrict__ hid,
    const float* __restrict__ rb1, const float* __restrict__ rW2, const float* __restrict__ rb2,
    const float* __restrict__ al, const float* __restrict__ O, u16* __restrict__ mixed) {
  const int tok = blockIdx.x;
  const int b = tok >> 12, t = tok & 4095;
  const int tid = threadIdx.x;
  __shared__ float lred[4][8];
  __shared__ float wgt[8];
  __shared__ float ta[8];
  const float hv = fmaxf(hid[(long)tok * 256 + tid] + rb1[tid], 0.f);
  const float4* w4 = (const float4*)(rW2 + tid * 8);
  const float4 wa = w4[0], wb = w4[1];
  float part[8] = {hv * wa.x, hv * wa.y, hv * wa.z, hv * wa.w,
                   hv * wb.x, hv * wb.y, hv * wb.z, hv * wb.w};
#pragma unroll
  for (int h = 0; h < 8; ++h) {
    float v = part[h];
#pragma unroll
    for (int o = 1; o < 64; o <<= 1) v += __shfl_xor(v, o);
    if ((tid & 63) == 0) lred[tid >> 6][h] = v;
  }
  __syncthreads();
  if (tid < 8) ta[tid] = tanhf(al[tid]);
  if (tid == 0) {
    float lg[8], m = -1e30f;
#pragma unroll
    for (int h = 0; h < 8; ++h) {
      lg[h] = lred[0][h] + lred[1][h] + lred[2][h] + lred[3][h] + rb2[h];
      m = fmaxf(m, lg[h]);
    }
    float s = 0.f;
#pragma unroll
    for (int h = 0; h < 8; ++h) { lg[h] = __expf(lg[h] - m); s += lg[h]; }
    const float inv = 1.f / s;
#pragma unroll
    for (int h = 0; h < 8; ++h) wgt[h] = lg[h] * inv;
  }
  __syncthreads();
  if (tid < 128) {
    const long base = (long)tok * 1024 + tid;
    const long rbase = ((long)b * 4096 + (4095 - t)) * 1024 + tid;
    float acc = 0.f;
#pragma unroll
    for (int h = 0; h < 8; ++h)
      acc += wgt[h] * (O[base + h * 128] + ta[h] * O[rbase + h * 128]);
    mixed[(long)tok * 128 + tid] = f2bf(acc);
  }
}

extern "C" void kernel_launch(void* const* d_in, const int* in_sizes, int n_in,
                              void* d_out, int out_size, void* d_ws, size_t ws_size,
                              hipStream_t stream) {
  const float* x    = (const float*)d_in[0];
  const float* Wq   = (const float*)d_in[1];
  const float* Wk   = (const float*)d_in[2];
  const float* Wv   = (const float*)d_in[3];
  const float* bg   = (const float*)d_in[4];
  const float* al   = (const float*)d_in[5];
  const float* rW1  = (const float*)d_in[6];
  const float* rb1  = (const float*)d_in[7];
  const float* rW2  = (const float*)d_in[8];
  const float* rb2  = (const float*)d_in[9];
  const float* Wout = (const float*)d_in[10];
  float* out = (float*)d_out;

  // ---- arena (lifetime overlays, ~95.5 MB) ----
  const size_t MB = 1u << 20;
  char* w = (char*)d_ws;
  u16*   xbf   = (u16*)(w + 0);            // 16 MB [P0-P1]
  u16*   xp2   = (u16*)(w + 16 * MB);      //  8 MB [P0-P1]
  u16*   xp4   = (u16*)(w + 24 * MB);      //  4 MB [P0-P1]
  u16*   xp8   = (u16*)(w + 28 * MB);      //  2 MB [P0-P1]
  float* O     = (float*)(w + 0);          // 32 MB [P4-P5] overlays dead pools
  u16*   Qb    = (u16*)(w + 32 * MB);      // 16 MB [P1-P4]
  u16*   KV    = (u16*)(w + 48 * MB);      // 15 MB [P1-P2]
  u16*   Kp    = (u16*)(w + 48 * MB);      // 7.5MB [P3-P4] overlays dead KV
  u16*   KT    = (u16*)(w + 63 * MB);      // 7.5MB [P2-P3]
  u16*   VT    = (u16*)(w + 70 * MB + 512 * 1024); // 7.5MB [P2-P4]
  float* hid   = (float*)(w + 78 * MB);    //  8 MB [P1-P5]
  u16*   wqT   = (u16*)(w + 86 * MB);      //  2 MB
  u16*   kvT   = (u16*)(w + 88 * MB);      //  4 MB
  u16*   rw1T  = (u16*)(w + 92 * MB);      // 512 KB
  u16*   woutT = (u16*)(w + 92 * MB + 512 * 1024);   // 256 KB
  u16*   crep  = (u16*)(w + 92 * MB + 768 * 1024);   // 257 KB
  u16*   mixed = (u16*)(w + 93 * MB + 512 * 1024);   //  2 MB

  auto gemm = [&](const void* A, const void* Bt, void* C, int M, int N, int K,
                  int lda, int ldb, int ldc, long abs_, long bbs, long cbs,
                  int nz, float alpha, bool obf) {
    dim3 g(M / 128, N / 128, nz), blk(256);
    if (obf)
      gemm_bt<true><<<g, blk, 0, stream>>>((const u16*)A, (const u16*)Bt, C, K, lda, ldb, ldc, abs_, bbs, cbs, alpha);
    else
      gemm_bt<false><<<g, blk, 0, stream>>>((const u16*)A, (const u16*)Bt, C, K, lda, ldb, ldc, abs_, bbs, cbs, alpha);
  };

  // P0: fused pooling + weight transposes
  pool_all<<<dim3(1024), dim3(256), 0, stream>>>(x, xbf, xp2, xp4, xp8);
  wq_t<<<dim3(512, 1, 8), dim3(256), 0, stream>>>(Wq, wqT);
  wkv_t<<<dim3(2048, 1, 4), dim3(256), 0, stream>>>(Wk, Wv, kvT);
  t_f32<<<dim3(1024), dim3(256), 0, stream>>>(rW1, rw1T, 1024, 256);
  t_f32<<<dim3(512), dim3(256), 0, stream>>>(Wout, woutT, 128, 1024);

  // P1: projections + router hidden
  gemm(xbf, wqT, Qb, 8192, 1024, 1024, 1024, 1024, 1024, 0, 0, 0, 1, 1.f, true);
  const u16* xps[4] = {xbf, xp2, xp4, xp8};
  const long kvrow[4] = {0, 8192, 12288, 14336};
  const long ktoff[4] = {0, 2097152, 3145728, 3670016};
  for (int g = 0; g < 4; ++g) {
    const int Tk = 4096 >> g;
    gemm(xps[g], kvT + (long)g * 524288, KV + kvrow[g] * 512, 2 * Tk, 512, 1024,
         1024, 1024, 512, 0, 0, 0, 1, 1.f, true);
  }
  gemm(xbf, rw1T, hid, 8192, 256, 1024, 1024, 1024, 256, 0, 0, 0, 1, 1.f, false);

  // P2: K/V transposes + spectral kernel replicas
  for (int g = 0; g < 4; ++g) {
    const int Tk = 4096 >> g;
    tpose_kv<<<dim3(Tk / 32, 4, 8), dim3(256), 0, stream>>>(KV + kvrow[g] * 512, KT + ktoff[g], VT + ktoff[g], Tk);
  }
  irfft_c<<<dim3(16, 8), dim3(256), 0, stream>>>(bg, crep);

  // P3: circulant conv (all heads/batches), ISS*log2e folded in
  conv_k<<<dim3(32, 1, 16), dim3(256), 0, stream>>>(crep, KT, Kp);

  // P4: flash attention, XCD-pinned 1-D grid (8 XCDs x 96 slots)
  flash<<<dim3(768), dim3(512), 0, stream>>>(Qb, Kp, VT, O);

  // P5: router softmax + contra-flow mix, then output projection
  router_mix<<<dim3(8192), dim3(256), 0, stream>>>(hid, rb1, rW2, rb2, al, O, mixed);
  gemm(mixed, woutT, out, 8192, 1024, 128, 128, 128, 1024, 0, 0, 0, 1, 1.f, false);
}